// Round 1
// 698.959 us; speedup vs baseline: 1.2256x; 1.2256x over previous
//
#include <hip/hip_runtime.h>
#include <hip/hip_bf16.h>
#include <math.h>

typedef __hip_bfloat16 bf16;
typedef __bf16 bf16x8 __attribute__((ext_vector_type(8)));
typedef float f32x4 __attribute__((ext_vector_type(4)));

#define NTOK 768      // B*L
#define SEQ  384
#define DDIM 256
#define VOC  32000

__device__ __forceinline__ float bf2f(bf16 v) { return __bfloat162float(v); }

// dtype probe: energy_levels = linspace(0,1,256).
// f32 storage: ushort[1] = top half of 0.0f = 0. bf16 storage: ushort[1] = bf16(1/255) != 0.
__device__ __forceinline__ bool probe_bf(const void* energy) {
    return ((const unsigned short*)energy)[1] != 0;
}
__device__ __forceinline__ float ldin(const void* p, long i, bool bf) {
    return bf ? bf2f(((const bf16*)p)[i]) : ((const float*)p)[i];
}

// block-wide sum over 256 threads (4 waves). All threads return the sum.
__device__ __forceinline__ float blk_sum256(float v, float* red) {
    #pragma unroll
    for (int o = 32; o > 0; o >>= 1) v += __shfl_down(v, o, 64);
    int w = threadIdx.x >> 6;
    __syncthreads();                       // protect red reuse across calls
    if ((threadIdx.x & 63) == 0) red[w] = v;
    __syncthreads();
    return red[0] + red[1] + red[2] + red[3];
}

// ---------------- Stage 1: embedding + EnhancedDynamicPhaseSpace ----------------
__global__ __launch_bounds__(256)
void phase_kernel(const int* __restrict__ x, const void* __restrict__ emb,
                  const void* __restrict__ lph, const void* __restrict__ iw,
                  const void* __restrict__ energy, const void* __restrict__ excf,
                  float* __restrict__ realO, float* __restrict__ imagO)
{
    __shared__ float red[4];
    bool bf = probe_bf(energy);
    int t = blockIdx.x, d = threadIdx.x;
    int tok = x[t];
    float re = ldin(emb, (long)tok * DDIM + d, bf) * 0.1f;
    float fr = 0.f, fi = 0.f;
    const float ca[3] = {1.0f, -0.5f, -0.5f};
    const float sa[3] = {0.0f, 0.86602540378443864676f, -0.86602540378443864676f};
    #pragma unroll
    for (int i = 0; i < 3; ++i) {
        float pa = tanhf(ldin(lph, i * DDIM + d, bf)) * 3.14159265358979323846f;
        pa = pa * 1.61803398874989484820f;
        float vr = re * cosf(pa);
        float vi = re * sinf(pa);
        float mu = blk_sum256(vr, red) * (1.f / 256.f);
        float dv = vr - mu;
        float var = blk_sum256(dv * dv, red) * (1.f / 256.f);
        float r = dv / sqrtf(var + 1e-8f);
        mu = blk_sum256(vi, red) * (1.f / 256.f);
        float di = vi - mu;
        var = blk_sum256(di * di, red) * (1.f / 256.f);
        float im = di / sqrtf(var + 1e-8f);
        float w = tanhf(ldin(iw, i * DDIM + d, bf));
        r *= w; im *= w;
        fr = fr + r * ca[i] - im * sa[i];
        fi = fi + r * sa[i] + im * ca[i];
    }
    float amp = sqrtf(fr * fr + fi * fi + 1e-8f);
    float ex = expf(ldin(energy, d, bf)) * ldin(excf, 0, bf);
    if (amp < 0.1f) { fr += ex; fi += ex; }
    float nrm = sqrtf(fr * fr + fi * fi + 1e-8f);
    float rr = fminf(fmaxf(fr / nrm, -1.f), 1.f);
    float ii = fminf(fmaxf(fi / nrm, -1.f), 1.f);
    realO[t * DDIM + d] = rr;
    imagO[t * DDIM + d] = ii;
}

// ---------------- Per-layer: LN + phase decomposition ----------------
__global__ __launch_bounds__(256)
void normphase_kernel(const float* __restrict__ realI, const float* __restrict__ imagI,
                      float* __restrict__ nrO, float* __restrict__ niO,
                      float* __restrict__ Co, float* __restrict__ So)
{
    __shared__ float red[4];
    int t = blockIdx.x, d = threadIdx.x;
    float r = realI[t * DDIM + d];
    float mu = blk_sum256(r, red) * (1.f / 256.f);
    float dv = r - mu;
    float var = blk_sum256(dv * dv, red) * (1.f / 256.f);
    float nr = dv / sqrtf(var + 1e-5f);
    float im = imagI[t * DDIM + d];
    mu = blk_sum256(im, red) * (1.f / 256.f);
    float di = im - mu;
    var = blk_sum256(di * di, red) * (1.f / 256.f);
    float ni = di / sqrtf(var + 1e-5f);
    float ph = atan2f(ni + 1e-8f, nr + 1e-8f);
    nrO[t * DDIM + d] = nr;
    niO[t * DDIM + d] = ni;
    Co[t * DDIM + d] = cosf(ph);
    So[t * DDIM + d] = sinf(ph);
}

// partial column sums of C,S over the sequence (for coherence)
__global__ __launch_bounds__(256)
void sums_kernel(const float* __restrict__ C, const float* __restrict__ S,
                 float* __restrict__ Cp, float* __restrict__ Sp)
{
    int c = blockIdx.x, b = blockIdx.y, d = threadIdx.x;
    float cs = 0.f, ss = 0.f;
    int base = (b * SEQ + c * 48) * DDIM + d;
    for (int m = 0; m < 48; ++m) { cs += C[base + m * DDIM]; ss += S[base + m * DDIM]; }
    Cp[(b * 8 + c) * DDIM + d] = cs;
    Sp[(b * 8 + c) * DDIM + d] = ss;
}

// scores[b,l,m] = scale * sum_d (C_l C_m + S_l S_m) * w_mean[d]
__global__ __launch_bounds__(256)
void scores_kernel(const float* __restrict__ C, const float* __restrict__ S,
                   const void* __restrict__ W, const void* __restrict__ energy,
                   int layer, float* __restrict__ scores)
{
    __shared__ float wm[DDIM];
    __shared__ float Ac[64][33], As[64][33], Bc[64][33], Bs[64][33];
    bool bf = probe_bf(energy);
    int m0 = blockIdx.x * 64, l0 = blockIdx.y * 64, b = blockIdx.z;
    int tid = threadIdx.x;
    {   // w_mean[d] = mean_j W[layer][d][j]
        float s = 0.f;
        long base = (long)layer * DDIM * DDIM + (long)tid * DDIM;
        if (bf) {
            const bf16* row = (const bf16*)W + base;
            for (int j = 0; j < DDIM; ++j) s += bf2f(row[j]);
        } else {
            const float* row = (const float*)W + base;
            for (int j = 0; j < DDIM; ++j) s += row[j];
        }
        wm[tid] = s * (1.f / 256.f);
    }
    __syncthreads();
    float acc[4][4] = {};
    int tx = tid & 15, ty = tid >> 4;
    for (int k0 = 0; k0 < DDIM; k0 += 32) {
        __syncthreads();
        #pragma unroll
        for (int i = 0; i < 8; ++i) {
            int flat = i * 256 + tid;
            int r = flat >> 5, k = flat & 31;
            float wv = wm[k0 + k];
            Ac[r][k] = C[(b * SEQ + l0 + r) * DDIM + k0 + k] * wv;
            As[r][k] = S[(b * SEQ + l0 + r) * DDIM + k0 + k] * wv;
            Bc[r][k] = C[(b * SEQ + m0 + r) * DDIM + k0 + k];
            Bs[r][k] = S[(b * SEQ + m0 + r) * DDIM + k0 + k];
        }
        __syncthreads();
        #pragma unroll
        for (int k = 0; k < 32; ++k) {
            float avc[4], avs[4], bvc[4], bvs[4];
            #pragma unroll
            for (int il = 0; il < 4; ++il) { avc[il] = Ac[ty * 4 + il][k]; avs[il] = As[ty * 4 + il][k]; }
            #pragma unroll
            for (int im = 0; im < 4; ++im) { bvc[im] = Bc[tx * 4 + im][k]; bvs[im] = Bs[tx * 4 + im][k]; }
            #pragma unroll
            for (int il = 0; il < 4; ++il)
                #pragma unroll
                for (int im = 0; im < 4; ++im)
                    acc[il][im] += avc[il] * bvc[im] + avs[il] * bvs[im];
        }
    }
    #pragma unroll
    for (int il = 0; il < 4; ++il)
        #pragma unroll
        for (int im = 0; im < 4; ++im)
            scores[(b * SEQ + l0 + ty * 4 + il) * SEQ + m0 + tx * 4 + im] = acc[il][im] * 0.0625f;
}

__global__ __launch_bounds__(384)
void softmax_kernel(float* __restrict__ scores, const int* __restrict__ x)
{
    __shared__ float red[6];
    int row = blockIdx.x;            // b*384 + l
    int b = row / SEQ;
    int m = threadIdx.x;
    float s = scores[row * SEQ + m];
    if (x[b * SEQ + m] == 0) s = -__builtin_inff();
    float v = s;
    #pragma unroll
    for (int o = 32; o > 0; o >>= 1) v = fmaxf(v, __shfl_down(v, o, 64));
    if ((threadIdx.x & 63) == 0) red[threadIdx.x >> 6] = v;
    __syncthreads();
    float mx = red[0];
    #pragma unroll
    for (int i = 1; i < 6; ++i) mx = fmaxf(mx, red[i]);
    float p = expf(s - mx);
    __syncthreads();
    v = p;
    #pragma unroll
    for (int o = 32; o > 0; o >>= 1) v += __shfl_down(v, o, 64);
    if ((threadIdx.x & 63) == 0) red[threadIdx.x >> 6] = v;
    __syncthreads();
    float sum = red[0] + red[1] + red[2] + red[3] + red[4] + red[5];
    float pv = p / sum;
    pv = fminf(fmaxf(pv, 1e-6f), 1.0f);
    scores[row * SEQ + m] = pv;
}

// out_r/out_i = attn @ nr/ni   per batch
__global__ __launch_bounds__(256)
void outgemm_kernel(const float* __restrict__ attn, const float* __restrict__ nr,
                    const float* __restrict__ ni, float* __restrict__ outr,
                    float* __restrict__ outi)
{
    __shared__ float At[64][33], Br[32][65], Bi[32][65];
    int d0 = blockIdx.x * 64, l0 = blockIdx.y * 64, b = blockIdx.z;
    int tid = threadIdx.x, tx = tid & 15, ty = tid >> 4;
    float accr[4][4] = {}, acci[4][4] = {};
    for (int k0 = 0; k0 < SEQ; k0 += 32) {
        __syncthreads();
        #pragma unroll
        for (int i = 0; i < 8; ++i) {
            int flat = i * 256 + tid;
            int r = flat >> 5, k = flat & 31;
            At[r][k] = attn[(b * SEQ + l0 + r) * SEQ + k0 + k];
        }
        #pragma unroll
        for (int i = 0; i < 8; ++i) {
            int flat = i * 256 + tid;
            int r = flat >> 6, c = flat & 63;
            Br[r][c] = nr[(b * SEQ + k0 + r) * DDIM + d0 + c];
            Bi[r][c] = ni[(b * SEQ + k0 + r) * DDIM + d0 + c];
        }
        __syncthreads();
        #pragma unroll
        for (int k = 0; k < 32; ++k) {
            float a[4], brv[4], biv[4];
            #pragma unroll
            for (int il = 0; il < 4; ++il) a[il] = At[ty * 4 + il][k];
            #pragma unroll
            for (int id = 0; id < 4; ++id) { brv[id] = Br[k][tx * 4 + id]; biv[id] = Bi[k][tx * 4 + id]; }
            #pragma unroll
            for (int il = 0; il < 4; ++il)
                #pragma unroll
                for (int id = 0; id < 4; ++id) {
                    accr[il][id] += a[il] * brv[id];
                    acci[il][id] += a[il] * biv[id];
                }
        }
    }
    #pragma unroll
    for (int il = 0; il < 4; ++il)
        #pragma unroll
        for (int id = 0; id < 4; ++id) {
            int idx = (b * SEQ + l0 + ty * 4 + il) * DDIM + d0 + tx * 4 + id;
            outr[idx] = accr[il][id];
            outi[idx] = acci[il][id];
        }
}

// coherence + phase preservation + residual LN update
__global__ __launch_bounds__(256)
void update_kernel(float* __restrict__ realA, float* __restrict__ imagA,
                   const float* __restrict__ outr, const float* __restrict__ outi,
                   const float* __restrict__ C, const float* __restrict__ S,
                   const float* __restrict__ Cp, const float* __restrict__ Sp,
                   const void* __restrict__ pp, const void* __restrict__ cfac,
                   const void* __restrict__ energy, int layer)
{
    __shared__ float red[4];
    bool bf = probe_bf(energy);
    int t = blockIdx.x, d = threadIdx.x;
    int b = t / SEQ;
    float cs = 0.f, ss = 0.f;
    #pragma unroll
    for (int c = 0; c < 8; ++c) {
        cs += Cp[(b * 8 + c) * DDIM + d];
        ss += Sp[(b * 8 + c) * DDIM + d];
    }
    float dotv = C[t * DDIM + d] * cs + S[t * DDIM + d] * ss;
    float coh = blk_sum256(dotv, red) * (1.0f / (384.f * 256.f));
    float cf = (1.f / (1.f + expf(-ldin(cfac, layer, bf)))) * coh;
    float orr = outr[t * DDIM + d], oii = outi[t * DDIM + d];
    float phase = atan2f(oii + 1e-8f, orr + 1e-8f);
    float pres = (1.f / (1.f + expf(-ldin(pp, layer * DDIM + d, bf)))) * cf;
    float pr = orr * cosf(phase * pres);
    float v = realA[t * DDIM + d] + 0.01f * pr;
    float mu = blk_sum256(v, red) * (1.f / 256.f);
    float dv = v - mu;
    float var = blk_sum256(dv * dv, red) * (1.f / 256.f);
    float nv = dv / sqrtf(var + 1e-8f);
    nv = fminf(fmaxf(nv, -1.f), 1.f);
    realA[t * DDIM + d] = nv;
    imagA[t * DDIM + d] = nv;   // reference bug: imag = real
}

// ---------------- Final stage, rebuilt around bf16x3 MFMA ----------------

// Fold out_w halves (K=512 -> 256), transpose to [v][d] (K-major), split bf16 hi/lo.
__global__ __launch_bounds__(256)
void fold_kernel(const void* __restrict__ W, const void* __restrict__ energy,
                 bf16* __restrict__ Bh, bf16* __restrict__ Bl)
{
    __shared__ float tile[64][65];
    bool bf = probe_bf(energy);
    int v0 = blockIdx.x * 64, d0 = blockIdx.y * 64;
    int c = threadIdx.x & 63, rr = threadIdx.x >> 6;
    #pragma unroll
    for (int i = 0; i < 16; ++i) {
        int r = i * 4 + rr;
        long i1 = (long)(d0 + r) * VOC + v0 + c;
        long i2 = (long)(d0 + r + 256) * VOC + v0 + c;
        tile[r][c] = ldin(W, i1, bf) + ldin(W, i2, bf);
    }
    __syncthreads();
    int d = threadIdx.x & 63, vv = threadIdx.x >> 6;
    #pragma unroll
    for (int i = 0; i < 16; ++i) {
        int v = i * 4 + vv;
        float s = tile[d][v];
        bf16 h = __float2bfloat16(s);
        long o = (long)(v0 + v) * DDIM + d0 + d;
        Bh[o] = h;
        Bl[o] = __float2bfloat16(s - __bfloat162float(h));
    }
}

// LN of realA (concat of duplicates == LN over D) -> comb split bf16 hi/lo
__global__ __launch_bounds__(256)
void prep_kernel(const float* __restrict__ realA, bf16* __restrict__ Ah,
                 bf16* __restrict__ Al)
{
    __shared__ float red[4];
    int t = blockIdx.x, d = threadIdx.x;
    float v = realA[t * DDIM + d];
    float mu = blk_sum256(v, red) * (1.f / 256.f);
    float dv = v - mu;
    float var = blk_sum256(dv * dv, red) * (1.f / 256.f);
    float cval = dv / sqrtf(var + 1e-5f);
    bf16 h = __float2bfloat16(cval);
    Ah[t * DDIM + d] = h;
    Al[t * DDIM + d] = __float2bfloat16(cval - __bfloat162float(h));
}

__device__ __forceinline__ void gload_lds16(const bf16* g, bf16* l) {
    __builtin_amdgcn_global_load_lds(
        (const __attribute__((address_space(1))) unsigned int*)g,
        (__attribute__((address_space(3))) unsigned int*)l,
        16, 0, 0);
}

// C[m][n] = clip((sum_k comb[m][k]*Wf[n][k] + bias[n]) * 0.1).
// bf16x3: acc = ch*wh + ch*wl + cl*wh  (error ~2^-16 relative, f32-equivalent)
// Tiles: BM=128, BN=128, BK=64. 4 waves; wave (wm,wn) owns 64x64.
__global__ __launch_bounds__(256, 2)
void vocab_gemm(const bf16* __restrict__ Ah, const bf16* __restrict__ Al,
                const bf16* __restrict__ Bh, const bf16* __restrict__ Bl,
                const void* __restrict__ bias, const void* __restrict__ energy,
                void* __restrict__ out)
{
    __shared__ bf16 lds[4][128 * 64];   // Ah, Al, Bh, Bl tiles: [row][64k], 128 B rows
    bool bf = probe_bf(energy);
    int m0 = blockIdx.x * 128, n0 = blockIdx.y * 128;
    int tid = threadIdx.x, lane = tid & 63, wid = tid >> 6;
    int wm = wid >> 1, wn = wid & 1;

    // one wave stages one tile; rows are 128 B -> 8 rows per global_load_lds
    const bf16* src;
    if      (wid == 0) src = Ah + (size_t)m0 * DDIM;
    else if (wid == 1) src = Al + (size_t)m0 * DDIM;
    else if (wid == 2) src = Bh + (size_t)n0 * DDIM;
    else               src = Bl + (size_t)n0 * DDIM;
    bf16* ldst = &lds[wid][0];
    int lrow = lane >> 3;                    // row within 8-row group
    int cbs  = (lane & 7) ^ lrow;            // pre-swizzled source col-block (16 B units)

    f32x4 acc[4][4] = {};

    for (int k0 = 0; k0 < DDIM; k0 += 64) {
        #pragma unroll
        for (int q = 0; q < 16; ++q) {
            const bf16* g = src + (size_t)(q * 8 + lrow) * DDIM + k0 + cbs * 8;
            gload_lds16(g, ldst + q * 512);  // linear dest; source pre-swizzled
        }
        __syncthreads();                     // drains vmcnt before barrier

        #pragma unroll
        for (int ks = 0; ks < 2; ++ks) {
            int cb = ks * 64 + (lane >> 4) * 16;       // byte col for this lane's k-group
            bf16x8 bhf[4], blf[4];
            #pragma unroll
            for (int fn = 0; fn < 4; ++fn) {
                int row = wn * 64 + fn * 16 + (lane & 15);
                int off = row * 128 + (cb ^ ((row & 7) << 4));
                bhf[fn] = *(const bf16x8*)((const char*)&lds[2][0] + off);
                blf[fn] = *(const bf16x8*)((const char*)&lds[3][0] + off);
            }
            #pragma unroll
            for (int fm = 0; fm < 4; ++fm) {
                int row = wm * 64 + fm * 16 + (lane & 15);
                int off = row * 128 + (cb ^ ((row & 7) << 4));
                bf16x8 ah = *(const bf16x8*)((const char*)&lds[0][0] + off);
                bf16x8 al = *(const bf16x8*)((const char*)&lds[1][0] + off);
                #pragma unroll
                for (int fn = 0; fn < 4; ++fn) {
                    acc[fm][fn] = __builtin_amdgcn_mfma_f32_16x16x32_bf16(ah, bhf[fn], acc[fm][fn], 0, 0, 0);
                    acc[fm][fn] = __builtin_amdgcn_mfma_f32_16x16x32_bf16(ah, blf[fn], acc[fm][fn], 0, 0, 0);
                    acc[fm][fn] = __builtin_amdgcn_mfma_f32_16x16x32_bf16(al, bhf[fn], acc[fm][fn], 0, 0, 0);
                }
            }
        }
        __syncthreads();
    }

    // epilogue: D[row=(lane>>4)*4+i][col=lane&15] per 16x16 fragment
    #pragma unroll
    for (int fn = 0; fn < 4; ++fn) {
        int n = n0 + wn * 64 + fn * 16 + (lane & 15);
        float bv = ldin(bias, n, bf);
        #pragma unroll
        for (int fm = 0; fm < 4; ++fm) {
            int mbase = m0 + wm * 64 + fm * 16 + (lane >> 4) * 4;
            #pragma unroll
            for (int i = 0; i < 4; ++i) {
                float lg = (acc[fm][fn][i] + bv) * 0.1f;
                lg = fminf(fmaxf(lg, -10.f), 10.f);
                size_t idx = (size_t)(mbase + i) * VOC + n;
                if (bf) ((bf16*)out)[idx] = __float2bfloat16(lg);
                else    ((float*)out)[idx] = lg;
            }
        }
    }
}

extern "C" void kernel_launch(void* const* d_in, const int* in_sizes, int n_in,
                              void* d_out, int out_size, void* d_ws, size_t ws_size,
                              hipStream_t stream) {
    (void)in_sizes; (void)n_in; (void)out_size; (void)ws_size;
    const int*  x        = (const int*)d_in[0];
    const void* emb_real = d_in[1];
    // d_in[2] = emb_imag: unused downstream (matches reference)
    const void* lph      = d_in[3];
    const void* iw       = d_in[4];
    const void* energy   = d_in[5];
    const void* excf     = d_in[6];
    const void* pp       = d_in[7];
    const void* cfac     = d_in[8];
    const void* Wattn    = d_in[9];
    const void* out_w    = d_in[10];
    const void* out_b    = d_in[11];

    float* ws = (float*)d_ws;
    const int TD = NTOK * DDIM;   // 196608
    float* realA = ws;            // 0
    float* imagA = realA + TD;    // 1
    float* nr    = imagA + TD;    // 2
    float* ni    = nr + TD;       // 3
    float* Cc    = ni + TD;       // 4
    float* Ss    = Cc + TD;       // 5
    float* outr  = Ss + TD;       // 6
    float* outi  = outr + TD;     // 7
    float* attn  = outi + TD;     // 2*384*384
    float* Cp    = attn + 2 * SEQ * SEQ;   // 16*256
    float* Sp    = Cp + 16 * DDIM;
    // new final-stage buffers (bf16), 16B-aligned offsets
    bf16* Ah  = (bf16*)(Sp + 16 * DDIM);
    bf16* Al  = Ah + (size_t)NTOK * DDIM;
    bf16* Wth = Al + (size_t)NTOK * DDIM;
    bf16* Wtl = Wth + (size_t)VOC * DDIM;

    // fold/transpose/split W first (independent of everything else)
    fold_kernel<<<dim3(VOC / 64, DDIM / 64), 256, 0, stream>>>(out_w, energy, Wth, Wtl);

    phase_kernel<<<NTOK, 256, 0, stream>>>(x, emb_real, lph, iw, energy, excf, realA, imagA);
    for (int layer = 0; layer < 3; ++layer) {
        normphase_kernel<<<NTOK, 256, 0, stream>>>(realA, imagA, nr, ni, Cc, Ss);
        sums_kernel<<<dim3(8, 2), 256, 0, stream>>>(Cc, Ss, Cp, Sp);
        scores_kernel<<<dim3(6, 6, 2), 256, 0, stream>>>(Cc, Ss, Wattn, energy, layer, attn);
        softmax_kernel<<<NTOK, 384, 0, stream>>>(attn, x);
        outgemm_kernel<<<dim3(4, 6, 2), 256, 0, stream>>>(attn, nr, ni, outr, outi);
        update_kernel<<<NTOK, 256, 0, stream>>>(realA, imagA, outr, outi, Cc, Ss, Cp, Sp,
                                                pp, cfac, energy, layer);
    }
    prep_kernel<<<NTOK, 256, 0, stream>>>(realA, Ah, Al);
    vocab_gemm<<<dim3(NTOK / 128, VOC / 128), 256, 0, stream>>>(Ah, Al, Wth, Wtl, out_b, energy, (void*)d_out);
}

// Round 2
// 473.270 us; speedup vs baseline: 1.8101x; 1.4769x over previous
//
#include <hip/hip_runtime.h>
#include <hip/hip_bf16.h>
#include <math.h>

typedef __hip_bfloat16 bf16;
typedef __bf16 bf16x8 __attribute__((ext_vector_type(8)));
typedef float f32x4 __attribute__((ext_vector_type(4)));

#define NTOK 768      // B*L
#define SEQ  384
#define DDIM 256
#define VOC  32000

__device__ __forceinline__ float bf2f(bf16 v) { return __bfloat162float(v); }

// dtype probe: energy_levels = linspace(0,1,256).
// f32 storage: ushort[1] = top half of 0.0f = 0. bf16 storage: ushort[1] = bf16(1/255) != 0.
__device__ __forceinline__ bool probe_bf(const void* energy) {
    return ((const unsigned short*)energy)[1] != 0;
}
__device__ __forceinline__ float ldin(const void* p, long i, bool bf) {
    return bf ? bf2f(((const bf16*)p)[i]) : ((const float*)p)[i];
}

// block-wide sum over 256 threads (4 waves). All threads return the sum.
__device__ __forceinline__ float blk_sum256(float v, float* red) {
    #pragma unroll
    for (int o = 32; o > 0; o >>= 1) v += __shfl_down(v, o, 64);
    int w = threadIdx.x >> 6;
    __syncthreads();                       // protect red reuse across calls
    if ((threadIdx.x & 63) == 0) red[w] = v;
    __syncthreads();
    return red[0] + red[1] + red[2] + red[3];
}

// ---------------- Stage 1: embedding + EnhancedDynamicPhaseSpace ----------------
__global__ __launch_bounds__(256)
void phase_kernel(const int* __restrict__ x, const void* __restrict__ emb,
                  const void* __restrict__ lph, const void* __restrict__ iw,
                  const void* __restrict__ energy, const void* __restrict__ excf,
                  float* __restrict__ realO, float* __restrict__ imagO)
{
    __shared__ float red[4];
    bool bf = probe_bf(energy);
    int t = blockIdx.x, d = threadIdx.x;
    int tok = x[t];
    float re = ldin(emb, (long)tok * DDIM + d, bf) * 0.1f;
    float fr = 0.f, fi = 0.f;
    const float ca[3] = {1.0f, -0.5f, -0.5f};
    const float sa[3] = {0.0f, 0.86602540378443864676f, -0.86602540378443864676f};
    #pragma unroll
    for (int i = 0; i < 3; ++i) {
        float pa = tanhf(ldin(lph, i * DDIM + d, bf)) * 3.14159265358979323846f;
        pa = pa * 1.61803398874989484820f;
        float vr = re * cosf(pa);
        float vi = re * sinf(pa);
        float mu = blk_sum256(vr, red) * (1.f / 256.f);
        float dv = vr - mu;
        float var = blk_sum256(dv * dv, red) * (1.f / 256.f);
        float r = dv / sqrtf(var + 1e-8f);
        mu = blk_sum256(vi, red) * (1.f / 256.f);
        float di = vi - mu;
        var = blk_sum256(di * di, red) * (1.f / 256.f);
        float im = di / sqrtf(var + 1e-8f);
        float w = tanhf(ldin(iw, i * DDIM + d, bf));
        r *= w; im *= w;
        fr = fr + r * ca[i] - im * sa[i];
        fi = fi + r * sa[i] + im * ca[i];
    }
    float amp = sqrtf(fr * fr + fi * fi + 1e-8f);
    float ex = expf(ldin(energy, d, bf)) * ldin(excf, 0, bf);
    if (amp < 0.1f) { fr += ex; fi += ex; }
    float nrm = sqrtf(fr * fr + fi * fi + 1e-8f);
    float rr = fminf(fmaxf(fr / nrm, -1.f), 1.f);
    float ii = fminf(fmaxf(fi / nrm, -1.f), 1.f);
    realO[t * DDIM + d] = rr;
    imagO[t * DDIM + d] = ii;
}

// w_mean rows for all 3 layers, scale folded: wmAll[layer*256+d] = mean_j(W[l][d][j]) / 16
__global__ __launch_bounds__(256)
void wmean_kernel(const void* __restrict__ W, const void* __restrict__ energy,
                  float* __restrict__ wmAll)
{
    bool bf = probe_bf(energy);
    int row = blockIdx.x * 4 + (threadIdx.x >> 6);   // 0..767 = layer*256 + d
    int lane = threadIdx.x & 63;
    long base = (long)row * DDIM + lane * 4;
    float s = 0.f;
    #pragma unroll
    for (int j = 0; j < 4; ++j) s += ldin(W, base + j, bf);
    #pragma unroll
    for (int o = 32; o > 0; o >>= 1) s += __shfl_down(s, o, 64);
    if (lane == 0) wmAll[row] = s * (1.f / 256.f) * 0.0625f;
}

// ---------------- Per-layer: LN + phase decomposition ----------------
// Also emits bf16 hi/lo operands for the scores GEMM:
//   A[t][k] (k<256: C*wm, k>=256: S*wm), B[t][k] (k<256: C, k>=256: S), rows of 512.
__global__ __launch_bounds__(256)
void normphase_kernel(const float* __restrict__ realI, const float* __restrict__ imagI,
                      const float* __restrict__ wm,
                      float* __restrict__ nrO, float* __restrict__ niO,
                      float* __restrict__ Co, float* __restrict__ So,
                      bf16* __restrict__ ASh, bf16* __restrict__ ASl,
                      bf16* __restrict__ BSh, bf16* __restrict__ BSl)
{
    __shared__ float red[4];
    int t = blockIdx.x, d = threadIdx.x;
    float r = realI[t * DDIM + d];
    float mu = blk_sum256(r, red) * (1.f / 256.f);
    float dv = r - mu;
    float var = blk_sum256(dv * dv, red) * (1.f / 256.f);
    float nr = dv / sqrtf(var + 1e-5f);
    float im = imagI[t * DDIM + d];
    mu = blk_sum256(im, red) * (1.f / 256.f);
    float di = im - mu;
    var = blk_sum256(di * di, red) * (1.f / 256.f);
    float ni = di / sqrtf(var + 1e-5f);
    float ph = atan2f(ni + 1e-8f, nr + 1e-8f);
    float Cv = cosf(ph), Sv = sinf(ph);
    nrO[t * DDIM + d] = nr;
    niO[t * DDIM + d] = ni;
    Co[t * DDIM + d] = Cv;
    So[t * DDIM + d] = Sv;
    float wv = wm[d];
    float aC = Cv * wv, aS = Sv * wv;
    long o0 = (long)t * 512 + d, o1 = o0 + 256;
    bf16 h;
    h = __float2bfloat16(aC); ASh[o0] = h; ASl[o0] = __float2bfloat16(aC - bf2f(h));
    h = __float2bfloat16(aS); ASh[o1] = h; ASl[o1] = __float2bfloat16(aS - bf2f(h));
    h = __float2bfloat16(Cv); BSh[o0] = h; BSl[o0] = __float2bfloat16(Cv - bf2f(h));
    h = __float2bfloat16(Sv); BSh[o1] = h; BSl[o1] = __float2bfloat16(Sv - bf2f(h));
}

// partial column sums of C,S over the sequence (for coherence)
__global__ __launch_bounds__(256)
void sums_kernel(const float* __restrict__ C, const float* __restrict__ S,
                 float* __restrict__ Cp, float* __restrict__ Sp)
{
    int c = blockIdx.x, b = blockIdx.y, d = threadIdx.x;
    float cs = 0.f, ss = 0.f;
    int base = (b * SEQ + c * 48) * DDIM + d;
    for (int m = 0; m < 48; ++m) { cs += C[base + m * DDIM]; ss += S[base + m * DDIM]; }
    Cp[(b * 8 + c) * DDIM + d] = cs;
    Sp[(b * 8 + c) * DDIM + d] = ss;
}

__device__ __forceinline__ void gload_lds16(const bf16* g, bf16* l) {
    __builtin_amdgcn_global_load_lds(
        (const __attribute__((address_space(1))) unsigned int*)g,
        (__attribute__((address_space(3))) unsigned int*)l,
        16, 0, 0);
}

// scores[b,l,m] = A[b,l,:] . B[b,m,:]  (K=512, scale pre-folded into A)
// bf16x3 hi/lo MFMA, 64x64 tiles, 4 waves of 32x32.
__global__ __launch_bounds__(256, 2)
void scores_mfma(const bf16* __restrict__ ASh, const bf16* __restrict__ ASl,
                 const bf16* __restrict__ BSh, const bf16* __restrict__ BSl,
                 float* __restrict__ scores)
{
    __shared__ bf16 lds[4][64 * 64];   // Ah, Al, Bh, Bl tiles: rows of 128 B
    int l0 = blockIdx.x * 64, m0 = blockIdx.y * 64, b = blockIdx.z;
    int tid = threadIdx.x, lane = tid & 63, wid = tid >> 6;
    int wr = wid >> 1, wc = wid & 1;

    const bf16* src;
    if      (wid == 0) src = ASh + (size_t)(b * SEQ + l0) * 512;
    else if (wid == 1) src = ASl + (size_t)(b * SEQ + l0) * 512;
    else if (wid == 2) src = BSh + (size_t)(b * SEQ + m0) * 512;
    else               src = BSl + (size_t)(b * SEQ + m0) * 512;
    bf16* ldst = &lds[wid][0];
    int lrow = lane >> 3;
    int cbs  = (lane & 7) ^ lrow;            // pre-swizzled source col-block (16 B)

    f32x4 acc[2][2] = {};

    for (int k0 = 0; k0 < 512; k0 += 64) {
        #pragma unroll
        for (int q = 0; q < 8; ++q) {
            const bf16* g = src + (size_t)(q * 8 + lrow) * 512 + k0 + cbs * 8;
            gload_lds16(g, ldst + q * 512);  // linear dest; source pre-swizzled
        }
        __syncthreads();
        #pragma unroll
        for (int ks = 0; ks < 2; ++ks) {
            int cb = ks * 64 + (lane >> 4) * 16;
            bf16x8 bh[2], bl[2];
            #pragma unroll
            for (int fn = 0; fn < 2; ++fn) {
                int row = wc * 32 + fn * 16 + (lane & 15);
                int off = row * 128 + (cb ^ ((row & 7) << 4));
                bh[fn] = *(const bf16x8*)((const char*)&lds[2][0] + off);
                bl[fn] = *(const bf16x8*)((const char*)&lds[3][0] + off);
            }
            #pragma unroll
            for (int fm = 0; fm < 2; ++fm) {
                int row = wr * 32 + fm * 16 + (lane & 15);
                int off = row * 128 + (cb ^ ((row & 7) << 4));
                bf16x8 ah = *(const bf16x8*)((const char*)&lds[0][0] + off);
                bf16x8 al = *(const bf16x8*)((const char*)&lds[1][0] + off);
                #pragma unroll
                for (int fn = 0; fn < 2; ++fn) {
                    acc[fm][fn] = __builtin_amdgcn_mfma_f32_16x16x32_bf16(ah, bh[fn], acc[fm][fn], 0, 0, 0);
                    acc[fm][fn] = __builtin_amdgcn_mfma_f32_16x16x32_bf16(ah, bl[fn], acc[fm][fn], 0, 0, 0);
                    acc[fm][fn] = __builtin_amdgcn_mfma_f32_16x16x32_bf16(al, bh[fn], acc[fm][fn], 0, 0, 0);
                }
            }
        }
        __syncthreads();
    }

    #pragma unroll
    for (int fn = 0; fn < 2; ++fn) {
        int mm = m0 + wc * 32 + fn * 16 + (lane & 15);
        #pragma unroll
        for (int fm = 0; fm < 2; ++fm) {
            int lbase = l0 + wr * 32 + fm * 16 + (lane >> 4) * 4;
            #pragma unroll
            for (int i = 0; i < 4; ++i)
                scores[(size_t)(b * SEQ + lbase + i) * SEQ + mm] = acc[fm][fn][i];
        }
    }
}

__global__ __launch_bounds__(384)
void softmax_kernel(float* __restrict__ scores, const int* __restrict__ x)
{
    __shared__ float red[6];
    int row = blockIdx.x;            // b*384 + l
    int b = row / SEQ;
    int m = threadIdx.x;
    float s = scores[row * SEQ + m];
    if (x[b * SEQ + m] == 0) s = -__builtin_inff();
    float v = s;
    #pragma unroll
    for (int o = 32; o > 0; o >>= 1) v = fmaxf(v, __shfl_down(v, o, 64));
    if ((threadIdx.x & 63) == 0) red[threadIdx.x >> 6] = v;
    __syncthreads();
    float mx = red[0];
    #pragma unroll
    for (int i = 1; i < 6; ++i) mx = fmaxf(mx, red[i]);
    float p = expf(s - mx);
    __syncthreads();
    v = p;
    #pragma unroll
    for (int o = 32; o > 0; o >>= 1) v += __shfl_down(v, o, 64);
    if ((threadIdx.x & 63) == 0) red[threadIdx.x >> 6] = v;
    __syncthreads();
    float sum = red[0] + red[1] + red[2] + red[3] + red[4] + red[5];
    float pv = p / sum;
    pv = fminf(fmaxf(pv, 1e-6f), 1.0f);
    scores[row * SEQ + m] = pv;
}

// out_r/out_i = attn @ nr/ni   per batch
__global__ __launch_bounds__(256)
void outgemm_kernel(const float* __restrict__ attn, const float* __restrict__ nr,
                    const float* __restrict__ ni, float* __restrict__ outr,
                    float* __restrict__ outi)
{
    __shared__ float At[64][33], Br[32][65], Bi[32][65];
    int d0 = blockIdx.x * 64, l0 = blockIdx.y * 64, b = blockIdx.z;
    int tid = threadIdx.x, tx = tid & 15, ty = tid >> 4;
    float accr[4][4] = {}, acci[4][4] = {};
    for (int k0 = 0; k0 < SEQ; k0 += 32) {
        __syncthreads();
        #pragma unroll
        for (int i = 0; i < 8; ++i) {
            int flat = i * 256 + tid;
            int r = flat >> 5, k = flat & 31;
            At[r][k] = attn[(b * SEQ + l0 + r) * SEQ + k0 + k];
        }
        #pragma unroll
        for (int i = 0; i < 8; ++i) {
            int flat = i * 256 + tid;
            int r = flat >> 6, c = flat & 63;
            Br[r][c] = nr[(b * SEQ + k0 + r) * DDIM + d0 + c];
            Bi[r][c] = ni[(b * SEQ + k0 + r) * DDIM + d0 + c];
        }
        __syncthreads();
        #pragma unroll
        for (int k = 0; k < 32; ++k) {
            float a[4], brv[4], biv[4];
            #pragma unroll
            for (int il = 0; il < 4; ++il) a[il] = At[ty * 4 + il][k];
            #pragma unroll
            for (int id = 0; id < 4; ++id) { brv[id] = Br[k][tx * 4 + id]; biv[id] = Bi[k][tx * 4 + id]; }
            #pragma unroll
            for (int il = 0; il < 4; ++il)
                #pragma unroll
                for (int id = 0; id < 4; ++id) {
                    accr[il][id] += a[il] * brv[id];
                    acci[il][id] += a[il] * biv[id];
                }
        }
    }
    #pragma unroll
    for (int il = 0; il < 4; ++il)
        #pragma unroll
        for (int id = 0; id < 4; ++id) {
            int idx = (b * SEQ + l0 + ty * 4 + il) * DDIM + d0 + tx * 4 + id;
            outr[idx] = accr[il][id];
            outi[idx] = acci[il][id];
        }
}

// coherence + phase preservation + residual LN update
__global__ __launch_bounds__(256)
void update_kernel(float* __restrict__ realA, float* __restrict__ imagA,
                   const float* __restrict__ outr, const float* __restrict__ outi,
                   const float* __restrict__ C, const float* __restrict__ S,
                   const float* __restrict__ Cp, const float* __restrict__ Sp,
                   const void* __restrict__ pp, const void* __restrict__ cfac,
                   const void* __restrict__ energy, int layer)
{
    __shared__ float red[4];
    bool bf = probe_bf(energy);
    int t = blockIdx.x, d = threadIdx.x;
    int b = t / SEQ;
    float cs = 0.f, ss = 0.f;
    #pragma unroll
    for (int c = 0; c < 8; ++c) {
        cs += Cp[(b * 8 + c) * DDIM + d];
        ss += Sp[(b * 8 + c) * DDIM + d];
    }
    float dotv = C[t * DDIM + d] * cs + S[t * DDIM + d] * ss;
    float coh = blk_sum256(dotv, red) * (1.0f / (384.f * 256.f));
    float cf = (1.f / (1.f + expf(-ldin(cfac, layer, bf)))) * coh;
    float orr = outr[t * DDIM + d], oii = outi[t * DDIM + d];
    float phase = atan2f(oii + 1e-8f, orr + 1e-8f);
    float pres = (1.f / (1.f + expf(-ldin(pp, layer * DDIM + d, bf)))) * cf;
    float pr = orr * cosf(phase * pres);
    float v = realA[t * DDIM + d] + 0.01f * pr;
    float mu = blk_sum256(v, red) * (1.f / 256.f);
    float dv = v - mu;
    float var = blk_sum256(dv * dv, red) * (1.f / 256.f);
    float nv = dv / sqrtf(var + 1e-8f);
    nv = fminf(fmaxf(nv, -1.f), 1.f);
    realA[t * DDIM + d] = nv;
    imagA[t * DDIM + d] = nv;   // reference bug: imag = real
}

// ---------------- Final stage: bf16x3 MFMA vocab GEMM ----------------

// Fold out_w halves (K=512 -> 256), transpose to [v][d] (K-major), split bf16 hi/lo.
__global__ __launch_bounds__(256)
void fold_kernel(const void* __restrict__ W, const void* __restrict__ energy,
                 bf16* __restrict__ Bh, bf16* __restrict__ Bl)
{
    __shared__ float tile[64][65];
    bool bf = probe_bf(energy);
    int v0 = blockIdx.x * 64, d0 = blockIdx.y * 64;
    int c = threadIdx.x & 63, rr = threadIdx.x >> 6;
    #pragma unroll
    for (int i = 0; i < 16; ++i) {
        int r = i * 4 + rr;
        long i1 = (long)(d0 + r) * VOC + v0 + c;
        long i2 = (long)(d0 + r + 256) * VOC + v0 + c;
        tile[r][c] = ldin(W, i1, bf) + ldin(W, i2, bf);
    }
    __syncthreads();
    int d = threadIdx.x & 63, vv = threadIdx.x >> 6;
    #pragma unroll
    for (int i = 0; i < 16; ++i) {
        int v = i * 4 + vv;
        float s = tile[d][v];
        bf16 h = __float2bfloat16(s);
        long o = (long)(v0 + v) * DDIM + d0 + d;
        Bh[o] = h;
        Bl[o] = __float2bfloat16(s - __bfloat162float(h));
    }
}

// LN of realA (concat of duplicates == LN over D) -> comb split bf16 hi/lo
__global__ __launch_bounds__(256)
void prep_kernel(const float* __restrict__ realA, bf16* __restrict__ Ah,
                 bf16* __restrict__ Al)
{
    __shared__ float red[4];
    int t = blockIdx.x, d = threadIdx.x;
    float v = realA[t * DDIM + d];
    float mu = blk_sum256(v, red) * (1.f / 256.f);
    float dv = v - mu;
    float var = blk_sum256(dv * dv, red) * (1.f / 256.f);
    float cval = dv / sqrtf(var + 1e-5f);
    bf16 h = __float2bfloat16(cval);
    Ah[t * DDIM + d] = h;
    Al[t * DDIM + d] = __float2bfloat16(cval - __bfloat162float(h));
}

// C[m][n] = clip((sum_k comb[m][k]*Wf[n][k] + bias[n]) * 0.1).
// bf16x3: acc = ch*wh + ch*wl + cl*wh  (error ~2^-16 relative, f32-equivalent)
// Tiles: BM=128, BN=128, BK=64. 4 waves; wave (wm,wn) owns 64x64.
__global__ __launch_bounds__(256, 2)
void vocab_gemm(const bf16* __restrict__ Ah, const bf16* __restrict__ Al,
                const bf16* __restrict__ Bh, const bf16* __restrict__ Bl,
                const void* __restrict__ bias, const void* __restrict__ energy,
                void* __restrict__ out)
{
    __shared__ bf16 lds[4][128 * 64];   // Ah, Al, Bh, Bl tiles: [row][64k], 128 B rows
    bool bf = probe_bf(energy);
    int m0 = blockIdx.x * 128, n0 = blockIdx.y * 128;
    int tid = threadIdx.x, lane = tid & 63, wid = tid >> 6;
    int wm = wid >> 1, wn = wid & 1;

    // one wave stages one tile; rows are 128 B -> 8 rows per global_load_lds
    const bf16* src;
    if      (wid == 0) src = Ah + (size_t)m0 * DDIM;
    else if (wid == 1) src = Al + (size_t)m0 * DDIM;
    else if (wid == 2) src = Bh + (size_t)n0 * DDIM;
    else               src = Bl + (size_t)n0 * DDIM;
    bf16* ldst = &lds[wid][0];
    int lrow = lane >> 3;                    // row within 8-row group
    int cbs  = (lane & 7) ^ lrow;            // pre-swizzled source col-block (16 B units)

    f32x4 acc[4][4] = {};

    for (int k0 = 0; k0 < DDIM; k0 += 64) {
        #pragma unroll
        for (int q = 0; q < 16; ++q) {
            const bf16* g = src + (size_t)(q * 8 + lrow) * DDIM + k0 + cbs * 8;
            gload_lds16(g, ldst + q * 512);  // linear dest; source pre-swizzled
        }
        __syncthreads();                     // drains vmcnt before barrier

        #pragma unroll
        for (int ks = 0; ks < 2; ++ks) {
            int cb = ks * 64 + (lane >> 4) * 16;       // byte col for this lane's k-group
            bf16x8 bhf[4], blf[4];
            #pragma unroll
            for (int fn = 0; fn < 4; ++fn) {
                int row = wn * 64 + fn * 16 + (lane & 15);
                int off = row * 128 + (cb ^ ((row & 7) << 4));
                bhf[fn] = *(const bf16x8*)((const char*)&lds[2][0] + off);
                blf[fn] = *(const bf16x8*)((const char*)&lds[3][0] + off);
            }
            #pragma unroll
            for (int fm = 0; fm < 4; ++fm) {
                int row = wm * 64 + fm * 16 + (lane & 15);
                int off = row * 128 + (cb ^ ((row & 7) << 4));
                bf16x8 ah = *(const bf16x8*)((const char*)&lds[0][0] + off);
                bf16x8 al = *(const bf16x8*)((const char*)&lds[1][0] + off);
                #pragma unroll
                for (int fn = 0; fn < 4; ++fn) {
                    acc[fm][fn] = __builtin_amdgcn_mfma_f32_16x16x32_bf16(ah, bhf[fn], acc[fm][fn], 0, 0, 0);
                    acc[fm][fn] = __builtin_amdgcn_mfma_f32_16x16x32_bf16(ah, blf[fn], acc[fm][fn], 0, 0, 0);
                    acc[fm][fn] = __builtin_amdgcn_mfma_f32_16x16x32_bf16(al, bhf[fn], acc[fm][fn], 0, 0, 0);
                }
            }
        }
        __syncthreads();
    }

    // epilogue: D[row=(lane>>4)*4+i][col=lane&15] per 16x16 fragment
    #pragma unroll
    for (int fn = 0; fn < 4; ++fn) {
        int n = n0 + wn * 64 + fn * 16 + (lane & 15);
        float bv = ldin(bias, n, bf);
        #pragma unroll
        for (int fm = 0; fm < 4; ++fm) {
            int mbase = m0 + wm * 64 + fm * 16 + (lane >> 4) * 4;
            #pragma unroll
            for (int i = 0; i < 4; ++i) {
                float lg = (acc[fm][fn][i] + bv) * 0.1f;
                lg = fminf(fmaxf(lg, -10.f), 10.f);
                size_t idx = (size_t)(mbase + i) * VOC + n;
                if (bf) ((bf16*)out)[idx] = __float2bfloat16(lg);
                else    ((float*)out)[idx] = lg;
            }
        }
    }
}

extern "C" void kernel_launch(void* const* d_in, const int* in_sizes, int n_in,
                              void* d_out, int out_size, void* d_ws, size_t ws_size,
                              hipStream_t stream) {
    (void)in_sizes; (void)n_in; (void)out_size; (void)ws_size;
    const int*  x        = (const int*)d_in[0];
    const void* emb_real = d_in[1];
    // d_in[2] = emb_imag: unused downstream (matches reference)
    const void* lph      = d_in[3];
    const void* iw       = d_in[4];
    const void* energy   = d_in[5];
    const void* excf     = d_in[6];
    const void* pp       = d_in[7];
    const void* cfac     = d_in[8];
    const void* Wattn    = d_in[9];
    const void* out_w    = d_in[10];
    const void* out_b    = d_in[11];

    float* ws = (float*)d_ws;
    const int TD = NTOK * DDIM;   // 196608
    float* realA = ws;            // 0
    float* imagA = realA + TD;    // 1
    float* nr    = imagA + TD;    // 2
    float* ni    = nr + TD;       // 3
    float* Cc    = ni + TD;       // 4
    float* Ss    = Cc + TD;       // 5
    float* outr  = Ss + TD;       // 6
    float* outi  = outr + TD;     // 7
    float* attn  = outi + TD;     // 2*384*384
    float* Cp    = attn + 2 * SEQ * SEQ;   // 16*256
    float* Sp    = Cp + 16 * DDIM;
    // final-stage buffers (bf16), 16B-aligned offsets
    bf16* Ah  = (bf16*)(Sp + 16 * DDIM);
    bf16* Al  = Ah + (size_t)NTOK * DDIM;
    bf16* Wth = Al + (size_t)NTOK * DDIM;
    bf16* Wtl = Wth + (size_t)VOC * DDIM;
    // scores-GEMM operands (K=512 rows), bf16 hi/lo
    bf16* ASh = Wtl + (size_t)VOC * DDIM;
    bf16* ASl = ASh + (size_t)NTOK * 512;
    bf16* BSh = ASl + (size_t)NTOK * 512;
    bf16* BSl = BSh + (size_t)NTOK * 512;
    float* wmAll = (float*)(BSl + (size_t)NTOK * 512);  // 768 floats

    // independent precomputes
    fold_kernel<<<dim3(VOC / 64, DDIM / 64), 256, 0, stream>>>(out_w, energy, Wth, Wtl);
    wmean_kernel<<<192, 256, 0, stream>>>(Wattn, energy, wmAll);

    phase_kernel<<<NTOK, 256, 0, stream>>>(x, emb_real, lph, iw, energy, excf, realA, imagA);
    for (int layer = 0; layer < 3; ++layer) {
        normphase_kernel<<<NTOK, 256, 0, stream>>>(realA, imagA, wmAll + layer * DDIM,
                                                   nr, ni, Cc, Ss, ASh, ASl, BSh, BSl);
        sums_kernel<<<dim3(8, 2), 256, 0, stream>>>(Cc, Ss, Cp, Sp);
        scores_mfma<<<dim3(6, 6, 2), 256, 0, stream>>>(ASh, ASl, BSh, BSl, attn);
        softmax_kernel<<<NTOK, 384, 0, stream>>>(attn, x);
        outgemm_kernel<<<dim3(4, 6, 2), 256, 0, stream>>>(attn, nr, ni, outr, outi);
        update_kernel<<<NTOK, 256, 0, stream>>>(realA, imagA, outr, outi, Cc, Ss, Cp, Sp,
                                                pp, cfac, energy, layer);
    }
    prep_kernel<<<NTOK, 256, 0, stream>>>(realA, Ah, Al);
    vocab_gemm<<<dim3(NTOK / 128, VOC / 128), 256, 0, stream>>>(Ah, Al, Wth, Wtl, out_b, energy, (void*)d_out);
}

// Round 3
// 384.615 us; speedup vs baseline: 2.2273x; 1.2305x over previous
//
#include <hip/hip_runtime.h>
#include <hip/hip_bf16.h>
#include <math.h>

typedef __hip_bfloat16 bf16;
typedef __bf16 bf16x8 __attribute__((ext_vector_type(8)));
typedef float f32x4 __attribute__((ext_vector_type(4)));

#define NTOK 768      // B*L
#define SEQ  384
#define DDIM 256
#define VOC  32000

__device__ __forceinline__ float bf2f(bf16 v) { return __bfloat162float(v); }

// dtype probe: energy_levels = linspace(0,1,256).
// f32 storage: ushort[1] = top half of 0.0f = 0. bf16 storage: ushort[1] = bf16(1/255) != 0.
__device__ __forceinline__ bool probe_bf(const void* energy) {
    return ((const unsigned short*)energy)[1] != 0;
}
__device__ __forceinline__ float ldin(const void* p, long i, bool bf) {
    return bf ? bf2f(((const bf16*)p)[i]) : ((const float*)p)[i];
}

// block-wide sum over 256 threads (4 waves). All threads return the sum.
__device__ __forceinline__ float blk_sum256(float v, float* red) {
    #pragma unroll
    for (int o = 32; o > 0; o >>= 1) v += __shfl_down(v, o, 64);
    int w = threadIdx.x >> 6;
    __syncthreads();                       // protect red reuse across calls
    if ((threadIdx.x & 63) == 0) red[w] = v;
    __syncthreads();
    return red[0] + red[1] + red[2] + red[3];
}

// ---------------- Stage 1: embedding + EnhancedDynamicPhaseSpace ----------------
__global__ __launch_bounds__(256)
void phase_kernel(const int* __restrict__ x, const void* __restrict__ emb,
                  const void* __restrict__ lph, const void* __restrict__ iw,
                  const void* __restrict__ energy, const void* __restrict__ excf,
                  float* __restrict__ realO, float* __restrict__ imagO)
{
    __shared__ float red[4];
    bool bf = probe_bf(energy);
    int t = blockIdx.x, d = threadIdx.x;
    int tok = x[t];
    float re = ldin(emb, (long)tok * DDIM + d, bf) * 0.1f;
    float fr = 0.f, fi = 0.f;
    const float ca[3] = {1.0f, -0.5f, -0.5f};
    const float sa[3] = {0.0f, 0.86602540378443864676f, -0.86602540378443864676f};
    #pragma unroll
    for (int i = 0; i < 3; ++i) {
        float pa = tanhf(ldin(lph, i * DDIM + d, bf)) * 3.14159265358979323846f;
        pa = pa * 1.61803398874989484820f;
        float vr = re * cosf(pa);
        float vi = re * sinf(pa);
        float mu = blk_sum256(vr, red) * (1.f / 256.f);
        float dv = vr - mu;
        float var = blk_sum256(dv * dv, red) * (1.f / 256.f);
        float r = dv / sqrtf(var + 1e-8f);
        mu = blk_sum256(vi, red) * (1.f / 256.f);
        float di = vi - mu;
        var = blk_sum256(di * di, red) * (1.f / 256.f);
        float im = di / sqrtf(var + 1e-8f);
        float w = tanhf(ldin(iw, i * DDIM + d, bf));
        r *= w; im *= w;
        fr = fr + r * ca[i] - im * sa[i];
        fi = fi + r * sa[i] + im * ca[i];
    }
    float amp = sqrtf(fr * fr + fi * fi + 1e-8f);
    float ex = expf(ldin(energy, d, bf)) * ldin(excf, 0, bf);
    if (amp < 0.1f) { fr += ex; fi += ex; }
    float nrm = sqrtf(fr * fr + fi * fi + 1e-8f);
    float rr = fminf(fmaxf(fr / nrm, -1.f), 1.f);
    float ii = fminf(fmaxf(fi / nrm, -1.f), 1.f);
    realO[t * DDIM + d] = rr;
    imagO[t * DDIM + d] = ii;
}

// w_mean rows for all 3 layers, scale folded: wmAll[layer*256+d] = mean_j(W[l][d][j]) / 16
__global__ __launch_bounds__(256)
void wmean_kernel(const void* __restrict__ W, const void* __restrict__ energy,
                  float* __restrict__ wmAll)
{
    bool bf = probe_bf(energy);
    int row = blockIdx.x * 4 + (threadIdx.x >> 6);   // 0..767 = layer*256 + d
    int lane = threadIdx.x & 63;
    long base = (long)row * DDIM + lane * 4;
    float s = 0.f;
    #pragma unroll
    for (int j = 0; j < 4; ++j) s += ldin(W, base + j, bf);
    #pragma unroll
    for (int o = 32; o > 0; o >>= 1) s += __shfl_down(s, o, 64);
    if (lane == 0) wmAll[row] = s * (1.f / 256.f) * 0.0625f;
}

// ---------------- Per-layer: LN + phase decomposition ----------------
// Also emits bf16 hi/lo operands for the scores GEMM:
//   A[t][k] (k<256: C*wm, k>=256: S*wm), B[t][k] (k<256: C, k>=256: S), rows of 512.
__global__ __launch_bounds__(256)
void normphase_kernel(const float* __restrict__ realI, const float* __restrict__ imagI,
                      const float* __restrict__ wm,
                      float* __restrict__ nrO, float* __restrict__ niO,
                      float* __restrict__ Co, float* __restrict__ So,
                      bf16* __restrict__ ASh, bf16* __restrict__ ASl,
                      bf16* __restrict__ BSh, bf16* __restrict__ BSl)
{
    __shared__ float red[4];
    int t = blockIdx.x, d = threadIdx.x;
    float r = realI[t * DDIM + d];
    float mu = blk_sum256(r, red) * (1.f / 256.f);
    float dv = r - mu;
    float var = blk_sum256(dv * dv, red) * (1.f / 256.f);
    float nr = dv / sqrtf(var + 1e-5f);
    float im = imagI[t * DDIM + d];
    mu = blk_sum256(im, red) * (1.f / 256.f);
    float di = im - mu;
    var = blk_sum256(di * di, red) * (1.f / 256.f);
    float ni = di / sqrtf(var + 1e-5f);
    float ph = atan2f(ni + 1e-8f, nr + 1e-8f);
    float Cv = cosf(ph), Sv = sinf(ph);
    nrO[t * DDIM + d] = nr;
    niO[t * DDIM + d] = ni;
    Co[t * DDIM + d] = Cv;
    So[t * DDIM + d] = Sv;
    float wv = wm[d];
    float aC = Cv * wv, aS = Sv * wv;
    long o0 = (long)t * 512 + d, o1 = o0 + 256;
    bf16 h;
    h = __float2bfloat16(aC); ASh[o0] = h; ASl[o0] = __float2bfloat16(aC - bf2f(h));
    h = __float2bfloat16(aS); ASh[o1] = h; ASl[o1] = __float2bfloat16(aS - bf2f(h));
    h = __float2bfloat16(Cv); BSh[o0] = h; BSl[o0] = __float2bfloat16(Cv - bf2f(h));
    h = __float2bfloat16(Sv); BSh[o1] = h; BSl[o1] = __float2bfloat16(Sv - bf2f(h));
}

// partial column sums of C,S over the sequence (for coherence)
__global__ __launch_bounds__(256)
void sums_kernel(const float* __restrict__ C, const float* __restrict__ S,
                 float* __restrict__ Cp, float* __restrict__ Sp)
{
    int c = blockIdx.x, b = blockIdx.y, d = threadIdx.x;
    float cs = 0.f, ss = 0.f;
    int base = (b * SEQ + c * 48) * DDIM + d;
    for (int m = 0; m < 48; ++m) { cs += C[base + m * DDIM]; ss += S[base + m * DDIM]; }
    Cp[(b * 8 + c) * DDIM + d] = cs;
    Sp[(b * 8 + c) * DDIM + d] = ss;
}

// transpose nr/ni (f32 [t][d]) -> K-major bf16 hi/lo [b][d][m] for the PV GEMM B-operand
__global__ __launch_bounds__(256)
void transpose_kernel(const float* __restrict__ nr, const float* __restrict__ ni,
                      bf16* __restrict__ nrTh, bf16* __restrict__ nrTl,
                      bf16* __restrict__ niTh, bf16* __restrict__ niTl)
{
    __shared__ float tr[64][65], ti[64][65];
    int m0 = blockIdx.x * 64, d0 = blockIdx.y * 64, b = blockIdx.z;
    int c = threadIdx.x & 63, rr = threadIdx.x >> 6;
    #pragma unroll
    for (int i = 0; i < 16; ++i) {
        int r = i * 4 + rr;
        tr[r][c] = nr[(b * SEQ + m0 + r) * DDIM + d0 + c];
        ti[r][c] = ni[(b * SEQ + m0 + r) * DDIM + d0 + c];
    }
    __syncthreads();
    #pragma unroll
    for (int i = 0; i < 16; ++i) {
        int dd = i * 4 + rr;
        float vr = tr[c][dd], vi = ti[c][dd];
        long o = (long)(b * DDIM + d0 + dd) * SEQ + m0 + c;
        bf16 h;
        h = __float2bfloat16(vr); nrTh[o] = h; nrTl[o] = __float2bfloat16(vr - bf2f(h));
        h = __float2bfloat16(vi); niTh[o] = h; niTl[o] = __float2bfloat16(vi - bf2f(h));
    }
}

__device__ __forceinline__ void gload_lds16(const bf16* g, bf16* l) {
    __builtin_amdgcn_global_load_lds(
        (const __attribute__((address_space(1))) unsigned int*)g,
        (__attribute__((address_space(3))) unsigned int*)l,
        16, 0, 0);
}

// scores[b,l,m] = A[b,l,:] . B[b,m,:]  (K=512, scale pre-folded into A)
// bf16x3 hi/lo MFMA, 64x64 tiles, 4 waves of 32x32.
__global__ __launch_bounds__(256, 2)
void scores_mfma(const bf16* __restrict__ ASh, const bf16* __restrict__ ASl,
                 const bf16* __restrict__ BSh, const bf16* __restrict__ BSl,
                 float* __restrict__ scores)
{
    __shared__ bf16 lds[4][64 * 64];   // Ah, Al, Bh, Bl tiles: rows of 128 B
    int l0 = blockIdx.x * 64, m0 = blockIdx.y * 64, b = blockIdx.z;
    int tid = threadIdx.x, lane = tid & 63, wid = tid >> 6;
    int wr = wid >> 1, wc = wid & 1;

    const bf16* src;
    if      (wid == 0) src = ASh + (size_t)(b * SEQ + l0) * 512;
    else if (wid == 1) src = ASl + (size_t)(b * SEQ + l0) * 512;
    else if (wid == 2) src = BSh + (size_t)(b * SEQ + m0) * 512;
    else               src = BSl + (size_t)(b * SEQ + m0) * 512;
    bf16* ldst = &lds[wid][0];
    int lrow = lane >> 3;
    int cbs  = (lane & 7) ^ lrow;            // pre-swizzled source col-block (16 B)

    f32x4 acc[2][2] = {};

    for (int k0 = 0; k0 < 512; k0 += 64) {
        #pragma unroll
        for (int q = 0; q < 8; ++q) {
            const bf16* g = src + (size_t)(q * 8 + lrow) * 512 + k0 + cbs * 8;
            gload_lds16(g, ldst + q * 512);  // linear dest; source pre-swizzled
        }
        __syncthreads();
        #pragma unroll
        for (int ks = 0; ks < 2; ++ks) {
            int cb = ks * 64 + (lane >> 4) * 16;
            bf16x8 bh[2], bl[2];
            #pragma unroll
            for (int fn = 0; fn < 2; ++fn) {
                int row = wc * 32 + fn * 16 + (lane & 15);
                int off = row * 128 + (cb ^ ((row & 7) << 4));
                bh[fn] = *(const bf16x8*)((const char*)&lds[2][0] + off);
                bl[fn] = *(const bf16x8*)((const char*)&lds[3][0] + off);
            }
            #pragma unroll
            for (int fm = 0; fm < 2; ++fm) {
                int row = wr * 32 + fm * 16 + (lane & 15);
                int off = row * 128 + (cb ^ ((row & 7) << 4));
                bf16x8 ah = *(const bf16x8*)((const char*)&lds[0][0] + off);
                bf16x8 al = *(const bf16x8*)((const char*)&lds[1][0] + off);
                #pragma unroll
                for (int fn = 0; fn < 2; ++fn) {
                    acc[fm][fn] = __builtin_amdgcn_mfma_f32_16x16x32_bf16(ah, bh[fn], acc[fm][fn], 0, 0, 0);
                    acc[fm][fn] = __builtin_amdgcn_mfma_f32_16x16x32_bf16(ah, bl[fn], acc[fm][fn], 0, 0, 0);
                    acc[fm][fn] = __builtin_amdgcn_mfma_f32_16x16x32_bf16(al, bh[fn], acc[fm][fn], 0, 0, 0);
                }
            }
        }
        __syncthreads();
    }

    #pragma unroll
    for (int fn = 0; fn < 2; ++fn) {
        int mm = m0 + wc * 32 + fn * 16 + (lane & 15);
        #pragma unroll
        for (int fm = 0; fm < 2; ++fm) {
            int lbase = l0 + wr * 32 + fm * 16 + (lane >> 4) * 4;
            #pragma unroll
            for (int i = 0; i < 4; ++i)
                scores[(size_t)(b * SEQ + lbase + i) * SEQ + mm] = acc[fm][fn][i];
        }
    }
}

// softmax over scores; emits P as bf16 hi/lo (no f32 writeback needed downstream)
__global__ __launch_bounds__(384)
void softmax_kernel(const float* __restrict__ scores, const int* __restrict__ x,
                    bf16* __restrict__ Ph, bf16* __restrict__ Pl)
{
    __shared__ float red[6];
    int row = blockIdx.x;            // b*384 + l
    int b = row / SEQ;
    int m = threadIdx.x;
    float s = scores[row * SEQ + m];
    if (x[b * SEQ + m] == 0) s = -__builtin_inff();
    float v = s;
    #pragma unroll
    for (int o = 32; o > 0; o >>= 1) v = fmaxf(v, __shfl_down(v, o, 64));
    if ((threadIdx.x & 63) == 0) red[threadIdx.x >> 6] = v;
    __syncthreads();
    float mx = red[0];
    #pragma unroll
    for (int i = 1; i < 6; ++i) mx = fmaxf(mx, red[i]);
    float p = expf(s - mx);
    __syncthreads();
    v = p;
    #pragma unroll
    for (int o = 32; o > 0; o >>= 1) v += __shfl_down(v, o, 64);
    if ((threadIdx.x & 63) == 0) red[threadIdx.x >> 6] = v;
    __syncthreads();
    float sum = red[0] + red[1] + red[2] + red[3] + red[4] + red[5];
    float pv = p / sum;
    pv = fminf(fmaxf(pv, 1e-6f), 1.0f);
    bf16 h = __float2bfloat16(pv);
    Ph[(size_t)row * SEQ + m] = h;
    Pl[(size_t)row * SEQ + m] = __float2bfloat16(pv - bf2f(h));
}

// out_r/out_i = P @ nr / P @ ni  via bf16x3 MFMA.
// A = P[l][m] (K=384 rows), B = nrT/niT [d][m] (K=384 rows).
// Tile 64(M)x32(N), 4 waves of 32x16 each; grid (6, 8, 2).
__global__ __launch_bounds__(256, 4)
void outgemm_mfma(const bf16* __restrict__ Ph, const bf16* __restrict__ Pl,
                  const bf16* __restrict__ nrTh, const bf16* __restrict__ nrTl,
                  const bf16* __restrict__ niTh, const bf16* __restrict__ niTl,
                  float* __restrict__ outr, float* __restrict__ outi)
{
    __shared__ bf16 ldsA[2][64 * 64];   // Ph, Pl tiles
    __shared__ bf16 ldsB[4][32 * 64];   // nrTh, nrTl, niTh, niTl tiles
    int l0 = blockIdx.x * 64, d0 = blockIdx.y * 32, b = blockIdx.z;
    int tid = threadIdx.x, lane = tid & 63, wid = tid >> 6;
    int wr = wid >> 1, wc = wid & 1;
    int lrow = lane >> 3, cbs = (lane & 7) ^ lrow;

    const bf16* sA  = (wid == 0 ? Ph : Pl) + (size_t)(b * SEQ + l0) * SEQ;
    const bf16* sB1 = (wid == 2 ? nrTh : nrTl) + (size_t)(b * DDIM + d0) * SEQ;
    const bf16* sB2 = (wid == 2 ? niTh : niTl) + (size_t)(b * DDIM + d0) * SEQ;

    f32x4 accr[2] = {}, acci[2] = {};

    for (int k0 = 0; k0 < SEQ; k0 += 64) {
        if (wid < 2) {
            bf16* ld = &ldsA[wid][0];
            #pragma unroll
            for (int q = 0; q < 8; ++q)
                gload_lds16(sA + (size_t)(q * 8 + lrow) * SEQ + k0 + cbs * 8, ld + q * 512);
        } else {
            bf16* l1 = &ldsB[wid - 2][0];   // wid2->nrTh, wid3->nrTl
            bf16* l2 = &ldsB[wid][0];       // wid2->niTh, wid3->niTl
            #pragma unroll
            for (int q = 0; q < 4; ++q)
                gload_lds16(sB1 + (size_t)(q * 8 + lrow) * SEQ + k0 + cbs * 8, l1 + q * 512);
            #pragma unroll
            for (int q = 0; q < 4; ++q)
                gload_lds16(sB2 + (size_t)(q * 8 + lrow) * SEQ + k0 + cbs * 8, l2 + q * 512);
        }
        __syncthreads();
        #pragma unroll
        for (int ks = 0; ks < 2; ++ks) {
            int cb = ks * 64 + (lane >> 4) * 16;
            int rowb = wc * 16 + (lane & 15);
            int offb = rowb * 128 + (cb ^ ((rowb & 7) << 4));
            bf16x8 brh = *(const bf16x8*)((const char*)&ldsB[0][0] + offb);
            bf16x8 brl = *(const bf16x8*)((const char*)&ldsB[1][0] + offb);
            bf16x8 bih = *(const bf16x8*)((const char*)&ldsB[2][0] + offb);
            bf16x8 bil = *(const bf16x8*)((const char*)&ldsB[3][0] + offb);
            #pragma unroll
            for (int fm = 0; fm < 2; ++fm) {
                int rowa = wr * 32 + fm * 16 + (lane & 15);
                int offa = rowa * 128 + (cb ^ ((rowa & 7) << 4));
                bf16x8 ah = *(const bf16x8*)((const char*)&ldsA[0][0] + offa);
                bf16x8 al = *(const bf16x8*)((const char*)&ldsA[1][0] + offa);
                accr[fm] = __builtin_amdgcn_mfma_f32_16x16x32_bf16(ah, brh, accr[fm], 0, 0, 0);
                accr[fm] = __builtin_amdgcn_mfma_f32_16x16x32_bf16(ah, brl, accr[fm], 0, 0, 0);
                accr[fm] = __builtin_amdgcn_mfma_f32_16x16x32_bf16(al, brh, accr[fm], 0, 0, 0);
                acci[fm] = __builtin_amdgcn_mfma_f32_16x16x32_bf16(ah, bih, acci[fm], 0, 0, 0);
                acci[fm] = __builtin_amdgcn_mfma_f32_16x16x32_bf16(ah, bil, acci[fm], 0, 0, 0);
                acci[fm] = __builtin_amdgcn_mfma_f32_16x16x32_bf16(al, bih, acci[fm], 0, 0, 0);
            }
        }
        __syncthreads();
    }

    int d = d0 + wc * 16 + (lane & 15);
    #pragma unroll
    for (int fm = 0; fm < 2; ++fm) {
        int lb = l0 + wr * 32 + fm * 16 + (lane >> 4) * 4;
        #pragma unroll
        for (int i = 0; i < 4; ++i) {
            size_t idx = (size_t)(b * SEQ + lb + i) * DDIM + d;
            outr[idx] = accr[fm][i];
            outi[idx] = acci[fm][i];
        }
    }
}

// coherence + phase preservation + residual LN update
__global__ __launch_bounds__(256)
void update_kernel(float* __restrict__ realA, float* __restrict__ imagA,
                   const float* __restrict__ outr, const float* __restrict__ outi,
                   const float* __restrict__ C, const float* __restrict__ S,
                   const float* __restrict__ Cp, const float* __restrict__ Sp,
                   const void* __restrict__ pp, const void* __restrict__ cfac,
                   const void* __restrict__ energy, int layer)
{
    __shared__ float red[4];
    bool bf = probe_bf(energy);
    int t = blockIdx.x, d = threadIdx.x;
    int b = t / SEQ;
    float cs = 0.f, ss = 0.f;
    #pragma unroll
    for (int c = 0; c < 8; ++c) {
        cs += Cp[(b * 8 + c) * DDIM + d];
        ss += Sp[(b * 8 + c) * DDIM + d];
    }
    float dotv = C[t * DDIM + d] * cs + S[t * DDIM + d] * ss;
    float coh = blk_sum256(dotv, red) * (1.0f / (384.f * 256.f));
    float cf = (1.f / (1.f + expf(-ldin(cfac, layer, bf)))) * coh;
    float orr = outr[t * DDIM + d], oii = outi[t * DDIM + d];
    float phase = atan2f(oii + 1e-8f, orr + 1e-8f);
    float pres = (1.f / (1.f + expf(-ldin(pp, layer * DDIM + d, bf)))) * cf;
    float pr = orr * cosf(phase * pres);
    float v = realA[t * DDIM + d] + 0.01f * pr;
    float mu = blk_sum256(v, red) * (1.f / 256.f);
    float dv = v - mu;
    float var = blk_sum256(dv * dv, red) * (1.f / 256.f);
    float nv = dv / sqrtf(var + 1e-8f);
    nv = fminf(fmaxf(nv, -1.f), 1.f);
    realA[t * DDIM + d] = nv;
    imagA[t * DDIM + d] = nv;   // reference bug: imag = real
}

// ---------------- Final stage: bf16x3 MFMA vocab GEMM ----------------

// Fold out_w halves (K=512 -> 256), transpose to [v][d] (K-major), split bf16 hi/lo.
__global__ __launch_bounds__(256)
void fold_kernel(const void* __restrict__ W, const void* __restrict__ energy,
                 bf16* __restrict__ Bh, bf16* __restrict__ Bl)
{
    __shared__ float tile[64][65];
    bool bf = probe_bf(energy);
    int v0 = blockIdx.x * 64, d0 = blockIdx.y * 64;
    int c = threadIdx.x & 63, rr = threadIdx.x >> 6;
    #pragma unroll
    for (int i = 0; i < 16; ++i) {
        int r = i * 4 + rr;
        long i1 = (long)(d0 + r) * VOC + v0 + c;
        long i2 = (long)(d0 + r + 256) * VOC + v0 + c;
        tile[r][c] = ldin(W, i1, bf) + ldin(W, i2, bf);
    }
    __syncthreads();
    int d = threadIdx.x & 63, vv = threadIdx.x >> 6;
    #pragma unroll
    for (int i = 0; i < 16; ++i) {
        int v = i * 4 + vv;
        float s = tile[d][v];
        bf16 h = __float2bfloat16(s);
        long o = (long)(v0 + v) * DDIM + d0 + d;
        Bh[o] = h;
        Bl[o] = __float2bfloat16(s - __bfloat162float(h));
    }
}

// LN of realA (concat of duplicates == LN over D) -> comb split bf16 hi/lo
__global__ __launch_bounds__(256)
void prep_kernel(const float* __restrict__ realA, bf16* __restrict__ Ah,
                 bf16* __restrict__ Al)
{
    __shared__ float red[4];
    int t = blockIdx.x, d = threadIdx.x;
    float v = realA[t * DDIM + d];
    float mu = blk_sum256(v, red) * (1.f / 256.f);
    float dv = v - mu;
    float var = blk_sum256(dv * dv, red) * (1.f / 256.f);
    float cval = dv / sqrtf(var + 1e-5f);
    bf16 h = __float2bfloat16(cval);
    Ah[t * DDIM + d] = h;
    Al[t * DDIM + d] = __float2bfloat16(cval - __bfloat162float(h));
}

// C[m][n] = clip((sum_k comb[m][k]*Wf[n][k] + bias[n]) * 0.1).
// bf16x3: acc = ch*wh + ch*wl + cl*wh  (error ~2^-16 relative, f32-equivalent)
// Tiles: BM=128, BN=128, BK=64. 8 waves; wave (wm,wn) owns 64x32.
// XCD-aware bijective swizzle: 1500 blocks, q=187, r=4.
__global__ __launch_bounds__(512, 4)
void vocab_gemm(const bf16* __restrict__ Ah, const bf16* __restrict__ Al,
                const bf16* __restrict__ Bh, const bf16* __restrict__ Bl,
                const void* __restrict__ bias, const void* __restrict__ energy,
                void* __restrict__ out)
{
    __shared__ bf16 lds[4][128 * 64];   // Ah, Al, Bh, Bl tiles: [row][64k], 128 B rows
    bool bf = probe_bf(energy);
    int flat = blockIdx.x + blockIdx.y * 6;        // 0..1499
    int xcd = flat & 7, bidx = flat >> 3;
    int swz = (xcd < 4) ? xcd * 188 + bidx : 752 + (xcd - 4) * 187 + bidx;
    int m0 = (swz % 6) * 128, n0 = (swz / 6) * 128;
    int tid = threadIdx.x, lane = tid & 63, wid = tid >> 6;   // 8 waves
    int wm = wid >> 2, wn = wid & 3;
    int arr = wid >> 1, half = wid & 1;

    // wave pair (arr, half) stages rows [half*64, half*64+64) of tile arr
    const bf16* src;
    if      (arr == 0) src = Ah + (size_t)m0 * DDIM;
    else if (arr == 1) src = Al + (size_t)m0 * DDIM;
    else if (arr == 2) src = Bh + (size_t)n0 * DDIM;
    else               src = Bl + (size_t)n0 * DDIM;
    src += (size_t)half * 64 * DDIM;
    bf16* ldst = &lds[arr][half * 64 * 64];
    int lrow = lane >> 3;                    // row within 8-row group
    int cbs  = (lane & 7) ^ lrow;            // pre-swizzled source col-block (16 B units)

    f32x4 acc[4][2] = {};

    for (int k0 = 0; k0 < DDIM; k0 += 64) {
        #pragma unroll
        for (int q = 0; q < 8; ++q) {
            const bf16* g = src + (size_t)(q * 8 + lrow) * DDIM + k0 + cbs * 8;
            gload_lds16(g, ldst + q * 512);  // linear dest; source pre-swizzled
        }
        __syncthreads();                     // drains vmcnt before barrier

        #pragma unroll
        for (int ks = 0; ks < 2; ++ks) {
            int cb = ks * 64 + (lane >> 4) * 16;       // byte col for this lane's k-group
            bf16x8 bhf[2], blf[2];
            #pragma unroll
            for (int fn = 0; fn < 2; ++fn) {
                int row = wn * 32 + fn * 16 + (lane & 15);
                int off = row * 128 + (cb ^ ((row & 7) << 4));
                bhf[fn] = *(const bf16x8*)((const char*)&lds[2][0] + off);
                blf[fn] = *(const bf16x8*)((const char*)&lds[3][0] + off);
            }
            #pragma unroll
            for (int fm = 0; fm < 4; ++fm) {
                int row = wm * 64 + fm * 16 + (lane & 15);
                int off = row * 128 + (cb ^ ((row & 7) << 4));
                bf16x8 ah = *(const bf16x8*)((const char*)&lds[0][0] + off);
                bf16x8 al = *(const bf16x8*)((const char*)&lds[1][0] + off);
                #pragma unroll
                for (int fn = 0; fn < 2; ++fn) {
                    acc[fm][fn] = __builtin_amdgcn_mfma_f32_16x16x32_bf16(ah, bhf[fn], acc[fm][fn], 0, 0, 0);
                    acc[fm][fn] = __builtin_amdgcn_mfma_f32_16x16x32_bf16(ah, blf[fn], acc[fm][fn], 0, 0, 0);
                    acc[fm][fn] = __builtin_amdgcn_mfma_f32_16x16x32_bf16(al, bhf[fn], acc[fm][fn], 0, 0, 0);
                }
            }
        }
        __syncthreads();
    }

    // epilogue: D[row=(lane>>4)*4+i][col=lane&15] per 16x16 fragment
    #pragma unroll
    for (int fn = 0; fn < 2; ++fn) {
        int n = n0 + wn * 32 + fn * 16 + (lane & 15);
        float bv = ldin(bias, n, bf);
        #pragma unroll
        for (int fm = 0; fm < 4; ++fm) {
            int mbase = m0 + wm * 64 + fm * 16 + (lane >> 4) * 4;
            #pragma unroll
            for (int i = 0; i < 4; ++i) {
                float lg = (acc[fm][fn][i] + bv) * 0.1f;
                lg = fminf(fmaxf(lg, -10.f), 10.f);
                size_t idx = (size_t)(mbase + i) * VOC + n;
                if (bf) ((bf16*)out)[idx] = __float2bfloat16(lg);
                else    ((float*)out)[idx] = lg;
            }
        }
    }
}

extern "C" void kernel_launch(void* const* d_in, const int* in_sizes, int n_in,
                              void* d_out, int out_size, void* d_ws, size_t ws_size,
                              hipStream_t stream) {
    (void)in_sizes; (void)n_in; (void)out_size; (void)ws_size;
    const int*  x        = (const int*)d_in[0];
    const void* emb_real = d_in[1];
    // d_in[2] = emb_imag: unused downstream (matches reference)
    const void* lph      = d_in[3];
    const void* iw       = d_in[4];
    const void* energy   = d_in[5];
    const void* excf     = d_in[6];
    const void* pp       = d_in[7];
    const void* cfac     = d_in[8];
    const void* Wattn    = d_in[9];
    const void* out_w    = d_in[10];
    const void* out_b    = d_in[11];

    float* ws = (float*)d_ws;
    const int TD = NTOK * DDIM;   // 196608
    float* realA = ws;            // 0
    float* imagA = realA + TD;    // 1
    float* nr    = imagA + TD;    // 2
    float* ni    = nr + TD;       // 3
    float* Cc    = ni + TD;       // 4
    float* Ss    = Cc + TD;       // 5
    float* outr  = Ss + TD;       // 6
    float* outi  = outr + TD;     // 7
    float* attn  = outi + TD;     // 2*384*384
    float* Cp    = attn + 2 * SEQ * SEQ;   // 16*256
    float* Sp    = Cp + 16 * DDIM;
    // bf16 buffers (all offsets multiples of 8 elems -> 16B aligned)
    bf16* Ah  = (bf16*)(Sp + 16 * DDIM);
    bf16* Al  = Ah + (size_t)NTOK * DDIM;
    bf16* Wth = Al + (size_t)NTOK * DDIM;
    bf16* Wtl = Wth + (size_t)VOC * DDIM;
    bf16* ASh = Wtl + (size_t)VOC * DDIM;
    bf16* ASl = ASh + (size_t)NTOK * 512;
    bf16* BSh = ASl + (size_t)NTOK * 512;
    bf16* BSl = BSh + (size_t)NTOK * 512;
    bf16* Phb = BSl + (size_t)NTOK * 512;      // P hi: [768][384]
    bf16* Plb = Phb + (size_t)NTOK * SEQ;
    bf16* nrTh = Plb + (size_t)NTOK * SEQ;     // [2][256][384]
    bf16* nrTl = nrTh + (size_t)NTOK * DDIM;
    bf16* niTh = nrTl + (size_t)NTOK * DDIM;
    bf16* niTl = niTh + (size_t)NTOK * DDIM;
    float* wmAll = (float*)(niTl + (size_t)NTOK * DDIM);  // 768 floats

    // independent precomputes
    fold_kernel<<<dim3(VOC / 64, DDIM / 64), 256, 0, stream>>>(out_w, energy, Wth, Wtl);
    wmean_kernel<<<192, 256, 0, stream>>>(Wattn, energy, wmAll);

    phase_kernel<<<NTOK, 256, 0, stream>>>(x, emb_real, lph, iw, energy, excf, realA, imagA);
    for (int layer = 0; layer < 3; ++layer) {
        normphase_kernel<<<NTOK, 256, 0, stream>>>(realA, imagA, wmAll + layer * DDIM,
                                                   nr, ni, Cc, Ss, ASh, ASl, BSh, BSl);
        sums_kernel<<<dim3(8, 2), 256, 0, stream>>>(Cc, Ss, Cp, Sp);
        transpose_kernel<<<dim3(6, 4, 2), 256, 0, stream>>>(nr, ni, nrTh, nrTl, niTh, niTl);
        scores_mfma<<<dim3(6, 6, 2), 256, 0, stream>>>(ASh, ASl, BSh, BSl, attn);
        softmax_kernel<<<NTOK, 384, 0, stream>>>(attn, x, Phb, Plb);
        outgemm_mfma<<<dim3(6, 8, 2), 256, 0, stream>>>(Phb, Plb, nrTh, nrTl, niTh, niTl, outr, outi);
        update_kernel<<<NTOK, 256, 0, stream>>>(realA, imagA, outr, outi, Cc, Ss, Cp, Sp,
                                                pp, cfac, energy, layer);
    }
    prep_kernel<<<NTOK, 256, 0, stream>>>(realA, Ah, Al);
    vocab_gemm<<<dim3(6, VOC / 128), 512, 0, stream>>>(Ah, Al, Wth, Wtl, out_b, energy, (void*)d_out);
}

// Round 4
// 367.739 us; speedup vs baseline: 2.3295x; 1.0459x over previous
//
#include <hip/hip_runtime.h>
#include <hip/hip_bf16.h>
#include <math.h>

typedef __hip_bfloat16 bf16;
typedef __bf16 bf16x8 __attribute__((ext_vector_type(8)));
typedef float f32x4 __attribute__((ext_vector_type(4)));

#define NTOK 768      // B*L
#define SEQ  384
#define DDIM 256
#define VOC  32000

__device__ __forceinline__ float bf2f(bf16 v) { return __bfloat162float(v); }

// dtype probe: energy_levels = linspace(0,1,256).
// f32 storage: ushort[1] = top half of 0.0f = 0. bf16 storage: ushort[1] = bf16(1/255) != 0.
__device__ __forceinline__ bool probe_bf(const void* energy) {
    return ((const unsigned short*)energy)[1] != 0;
}
__device__ __forceinline__ float ldin(const void* p, long i, bool bf) {
    return bf ? bf2f(((const bf16*)p)[i]) : ((const float*)p)[i];
}

// block-wide sum over 256 threads (4 waves). All threads return the sum.
__device__ __forceinline__ float blk_sum256(float v, float* red) {
    #pragma unroll
    for (int o = 32; o > 0; o >>= 1) v += __shfl_down(v, o, 64);
    int w = threadIdx.x >> 6;
    __syncthreads();                       // protect red reuse across calls
    if ((threadIdx.x & 63) == 0) red[w] = v;
    __syncthreads();
    return red[0] + red[1] + red[2] + red[3];
}

// emit per-layer normphase outputs (C/S, f32 nr/ni for transpose, bf16 hi/lo GEMM operands)
__device__ __forceinline__ void np_emit(int t, int d, float nrv, float niv, bool dual,
                                        const float* __restrict__ wm,
                                        float* __restrict__ nrO, float* __restrict__ niO,
                                        float* __restrict__ Co, float* __restrict__ So,
                                        bf16* __restrict__ ASh, bf16* __restrict__ ASl,
                                        bf16* __restrict__ BSh, bf16* __restrict__ BSl)
{
    float ph = atan2f(niv + 1e-8f, nrv + 1e-8f);
    float Cv = cosf(ph), Sv = sinf(ph);
    long idx = (long)t * DDIM + d;
    nrO[idx] = nrv;
    if (dual) niO[idx] = niv;
    Co[idx] = Cv;
    So[idx] = Sv;
    float wv = wm[d];
    float aC = Cv * wv, aS = Sv * wv;
    long o0 = (long)t * 512 + d, o1 = o0 + 256;
    bf16 h;
    h = __float2bfloat16(aC); ASh[o0] = h; ASl[o0] = __float2bfloat16(aC - bf2f(h));
    h = __float2bfloat16(aS); ASh[o1] = h; ASl[o1] = __float2bfloat16(aS - bf2f(h));
    h = __float2bfloat16(Cv); BSh[o0] = h; BSl[o0] = __float2bfloat16(Cv - bf2f(h));
    h = __float2bfloat16(Sv); BSh[o1] = h; BSl[o1] = __float2bfloat16(Sv - bf2f(h));
}

// ---------------- Stage 1: embedding + phase space + normphase(layer 0) fused ----------------
__global__ __launch_bounds__(256)
void phase_kernel(const int* __restrict__ x, const void* __restrict__ emb,
                  const void* __restrict__ lph, const void* __restrict__ iw,
                  const void* __restrict__ energy, const void* __restrict__ excf,
                  const float* __restrict__ wm0,
                  float* __restrict__ realO,
                  float* __restrict__ nrO, float* __restrict__ niO,
                  float* __restrict__ Co, float* __restrict__ So,
                  bf16* __restrict__ ASh, bf16* __restrict__ ASl,
                  bf16* __restrict__ BSh, bf16* __restrict__ BSl)
{
    __shared__ float red[4];
    bool bf = probe_bf(energy);
    int t = blockIdx.x, d = threadIdx.x;
    int tok = x[t];
    float re = ldin(emb, (long)tok * DDIM + d, bf) * 0.1f;
    float fr = 0.f, fi = 0.f;
    const float ca[3] = {1.0f, -0.5f, -0.5f};
    const float sa[3] = {0.0f, 0.86602540378443864676f, -0.86602540378443864676f};
    #pragma unroll
    for (int i = 0; i < 3; ++i) {
        float pa = tanhf(ldin(lph, i * DDIM + d, bf)) * 3.14159265358979323846f;
        pa = pa * 1.61803398874989484820f;
        float vr = re * cosf(pa);
        float vi = re * sinf(pa);
        float mu = blk_sum256(vr, red) * (1.f / 256.f);
        float dv = vr - mu;
        float var = blk_sum256(dv * dv, red) * (1.f / 256.f);
        float r = dv / sqrtf(var + 1e-8f);
        mu = blk_sum256(vi, red) * (1.f / 256.f);
        float di = vi - mu;
        var = blk_sum256(di * di, red) * (1.f / 256.f);
        float im = di / sqrtf(var + 1e-8f);
        float w = tanhf(ldin(iw, i * DDIM + d, bf));
        r *= w; im *= w;
        fr = fr + r * ca[i] - im * sa[i];
        fi = fi + r * sa[i] + im * ca[i];
    }
    float amp = sqrtf(fr * fr + fi * fi + 1e-8f);
    float ex = expf(ldin(energy, d, bf)) * ldin(excf, 0, bf);
    if (amp < 0.1f) { fr += ex; fi += ex; }
    float nrm = sqrtf(fr * fr + fi * fi + 1e-8f);
    float rr = fminf(fmaxf(fr / nrm, -1.f), 1.f);
    float ii = fminf(fmaxf(fi / nrm, -1.f), 1.f);
    realO[t * DDIM + d] = rr;
    // fused normphase (layer 0, dual: real != imag)
    float mu = blk_sum256(rr, red) * (1.f / 256.f);
    float dv = rr - mu;
    float var = blk_sum256(dv * dv, red) * (1.f / 256.f);
    float nrv = dv / sqrtf(var + 1e-5f);
    mu = blk_sum256(ii, red) * (1.f / 256.f);
    float di = ii - mu;
    var = blk_sum256(di * di, red) * (1.f / 256.f);
    float niv = di / sqrtf(var + 1e-5f);
    np_emit(t, d, nrv, niv, true, wm0, nrO, niO, Co, So, ASh, ASl, BSh, BSl);
}

// w_mean rows for all 3 layers, scale folded: wmAll[layer*256+d] = mean_j(W[l][d][j]) / 16
__global__ __launch_bounds__(256)
void wmean_kernel(const void* __restrict__ W, const void* __restrict__ energy,
                  float* __restrict__ wmAll)
{
    bool bf = probe_bf(energy);
    int row = blockIdx.x * 4 + (threadIdx.x >> 6);   // 0..767 = layer*256 + d
    int lane = threadIdx.x & 63;
    long base = (long)row * DDIM + lane * 4;
    float s = 0.f;
    #pragma unroll
    for (int j = 0; j < 4; ++j) s += ldin(W, base + j, bf);
    #pragma unroll
    for (int o = 32; o > 0; o >>= 1) s += __shfl_down(s, o, 64);
    if (lane == 0) wmAll[row] = s * (1.f / 256.f) * 0.0625f;
}

// partial column sums of C,S over the sequence (for coherence); 24 partials per batch
__global__ __launch_bounds__(256)
void sums_kernel(const float* __restrict__ C, const float* __restrict__ S,
                 float* __restrict__ Cp, float* __restrict__ Sp)
{
    int c = blockIdx.x, b = blockIdx.y, d = threadIdx.x;
    float cs = 0.f, ss = 0.f;
    int base = (b * SEQ + c * 16) * DDIM + d;
    #pragma unroll
    for (int m = 0; m < 16; ++m) { cs += C[base + m * DDIM]; ss += S[base + m * DDIM]; }
    Cp[(b * 24 + c) * DDIM + d] = cs;
    Sp[(b * 24 + c) * DDIM + d] = ss;
}

// transpose nr/ni (f32 [t][d]) -> K-major bf16 hi/lo [b][d][m]; imag half only when dual
__global__ __launch_bounds__(256)
void transpose_kernel(const float* __restrict__ nr, const float* __restrict__ ni,
                      bf16* __restrict__ nrTh, bf16* __restrict__ nrTl,
                      bf16* __restrict__ niTh, bf16* __restrict__ niTl, int dual)
{
    __shared__ float tr[64][65], ti[64][65];
    int m0 = blockIdx.x * 64, d0 = blockIdx.y * 64, b = blockIdx.z;
    int c = threadIdx.x & 63, rr = threadIdx.x >> 6;
    #pragma unroll
    for (int i = 0; i < 16; ++i) {
        int r = i * 4 + rr;
        tr[r][c] = nr[(b * SEQ + m0 + r) * DDIM + d0 + c];
        if (dual) ti[r][c] = ni[(b * SEQ + m0 + r) * DDIM + d0 + c];
    }
    __syncthreads();
    #pragma unroll
    for (int i = 0; i < 16; ++i) {
        int dd = i * 4 + rr;
        long o = (long)(b * DDIM + d0 + dd) * SEQ + m0 + c;
        float vr = tr[c][dd];
        bf16 h;
        h = __float2bfloat16(vr); nrTh[o] = h; nrTl[o] = __float2bfloat16(vr - bf2f(h));
        if (dual) {
            float vi = ti[c][dd];
            h = __float2bfloat16(vi); niTh[o] = h; niTl[o] = __float2bfloat16(vi - bf2f(h));
        }
    }
}

__device__ __forceinline__ void gload_lds16(const bf16* g, bf16* l) {
    __builtin_amdgcn_global_load_lds(
        (const __attribute__((address_space(1))) unsigned int*)g,
        (__attribute__((address_space(3))) unsigned int*)l,
        16, 0, 0);
}

// scores[b,l,m] = A[b,l,:] . B[b,m,:]  (K=512, scale pre-folded into A)
// bf16x3 hi/lo MFMA, 64(l)x32(m) tiles -> 288 blocks. 4 waves of 32x16.
__global__ __launch_bounds__(256, 4)
void scores_mfma(const bf16* __restrict__ ASh, const bf16* __restrict__ ASl,
                 const bf16* __restrict__ BSh, const bf16* __restrict__ BSl,
                 float* __restrict__ scores)
{
    __shared__ bf16 ldsA[2][64 * 64];   // Ah, Al tiles: rows of 128 B
    __shared__ bf16 ldsB[2][32 * 64];   // Bh, Bl tiles
    int l0 = blockIdx.x * 64, m0 = blockIdx.y * 32, b = blockIdx.z;
    int tid = threadIdx.x, lane = tid & 63, wid = tid >> 6;
    int wr = wid >> 1, wc = wid & 1;
    int lrow = lane >> 3;
    int cbs  = (lane & 7) ^ lrow;            // pre-swizzled source col-block (16 B)

    const bf16* srcA = (wid == 1 ? ASl : ASh) + (size_t)(b * SEQ + l0) * 512;
    const bf16* srcB = (wid == 3 ? BSl : BSh) + (size_t)(b * SEQ + m0) * 512;

    f32x4 acc[2] = {};

    for (int k0 = 0; k0 < 512; k0 += 64) {
        if (wid < 2) {
            bf16* ld = &ldsA[wid][0];
            #pragma unroll
            for (int q = 0; q < 8; ++q)
                gload_lds16(srcA + (size_t)(q * 8 + lrow) * 512 + k0 + cbs * 8, ld + q * 512);
        } else {
            bf16* ld = &ldsB[wid - 2][0];
            #pragma unroll
            for (int q = 0; q < 4; ++q)
                gload_lds16(srcB + (size_t)(q * 8 + lrow) * 512 + k0 + cbs * 8, ld + q * 512);
        }
        __syncthreads();
        #pragma unroll
        for (int ks = 0; ks < 2; ++ks) {
            int cb = ks * 64 + (lane >> 4) * 16;
            int rowb = wc * 16 + (lane & 15);
            int offb = rowb * 128 + (cb ^ ((rowb & 7) << 4));
            bf16x8 bh = *(const bf16x8*)((const char*)&ldsB[0][0] + offb);
            bf16x8 bl = *(const bf16x8*)((const char*)&ldsB[1][0] + offb);
            #pragma unroll
            for (int fm = 0; fm < 2; ++fm) {
                int rowa = wr * 32 + fm * 16 + (lane & 15);
                int offa = rowa * 128 + (cb ^ ((rowa & 7) << 4));
                bf16x8 ah = *(const bf16x8*)((const char*)&ldsA[0][0] + offa);
                bf16x8 al = *(const bf16x8*)((const char*)&ldsA[1][0] + offa);
                acc[fm] = __builtin_amdgcn_mfma_f32_16x16x32_bf16(ah, bh, acc[fm], 0, 0, 0);
                acc[fm] = __builtin_amdgcn_mfma_f32_16x16x32_bf16(ah, bl, acc[fm], 0, 0, 0);
                acc[fm] = __builtin_amdgcn_mfma_f32_16x16x32_bf16(al, bh, acc[fm], 0, 0, 0);
            }
        }
        __syncthreads();
    }

    int mm = m0 + wc * 16 + (lane & 15);
    #pragma unroll
    for (int fm = 0; fm < 2; ++fm) {
        int lbase = l0 + wr * 32 + fm * 16 + (lane >> 4) * 4;
        #pragma unroll
        for (int i = 0; i < 4; ++i)
            scores[(size_t)(b * SEQ + lbase + i) * SEQ + mm] = acc[fm][i];
    }
}

// softmax over scores; emits P as bf16 hi/lo
__global__ __launch_bounds__(384)
void softmax_kernel(const float* __restrict__ scores, const int* __restrict__ x,
                    bf16* __restrict__ Ph, bf16* __restrict__ Pl)
{
    __shared__ float red[6];
    int row = blockIdx.x;            // b*384 + l
    int b = row / SEQ;
    int m = threadIdx.x;
    float s = scores[row * SEQ + m];
    if (x[b * SEQ + m] == 0) s = -__builtin_inff();
    float v = s;
    #pragma unroll
    for (int o = 32; o > 0; o >>= 1) v = fmaxf(v, __shfl_down(v, o, 64));
    if ((threadIdx.x & 63) == 0) red[threadIdx.x >> 6] = v;
    __syncthreads();
    float mx = red[0];
    #pragma unroll
    for (int i = 1; i < 6; ++i) mx = fmaxf(mx, red[i]);
    float p = expf(s - mx);
    __syncthreads();
    v = p;
    #pragma unroll
    for (int o = 32; o > 0; o >>= 1) v += __shfl_down(v, o, 64);
    if ((threadIdx.x & 63) == 0) red[threadIdx.x >> 6] = v;
    __syncthreads();
    float sum = red[0] + red[1] + red[2] + red[3] + red[4] + red[5];
    float pv = p / sum;
    pv = fminf(fmaxf(pv, 1e-6f), 1.0f);
    bf16 h = __float2bfloat16(pv);
    Ph[(size_t)row * SEQ + m] = h;
    Pl[(size_t)row * SEQ + m] = __float2bfloat16(pv - bf2f(h));
}

// out_r/out_i = P @ nr / P @ ni  via bf16x3 MFMA. imag product only when dual.
// Tile 64(l)x32(d), 4 waves of 32x16; grid (6, 8, 2).
__global__ __launch_bounds__(256, 4)
void outgemm_mfma(const bf16* __restrict__ Ph, const bf16* __restrict__ Pl,
                  const bf16* __restrict__ nrTh, const bf16* __restrict__ nrTl,
                  const bf16* __restrict__ niTh, const bf16* __restrict__ niTl,
                  float* __restrict__ outr, float* __restrict__ outi, int dual)
{
    __shared__ bf16 ldsA[2][64 * 64];   // Ph, Pl tiles
    __shared__ bf16 ldsB[4][32 * 64];   // nrTh, nrTl, (niTh, niTl when dual)
    int l0 = blockIdx.x * 64, d0 = blockIdx.y * 32, b = blockIdx.z;
    int tid = threadIdx.x, lane = tid & 63, wid = tid >> 6;
    int wr = wid >> 1, wc = wid & 1;
    int lrow = lane >> 3, cbs = (lane & 7) ^ lrow;

    const bf16* sA  = (wid == 0 ? Ph : Pl) + (size_t)(b * SEQ + l0) * SEQ;
    const bf16* sB1 = (wid == 2 ? nrTh : nrTl) + (size_t)(b * DDIM + d0) * SEQ;
    const bf16* sB2 = (wid == 2 ? niTh : niTl) + (size_t)(b * DDIM + d0) * SEQ;

    f32x4 accr[2] = {}, acci[2] = {};

    for (int k0 = 0; k0 < SEQ; k0 += 64) {
        if (wid < 2) {
            bf16* ld = &ldsA[wid][0];
            #pragma unroll
            for (int q = 0; q < 8; ++q)
                gload_lds16(sA + (size_t)(q * 8 + lrow) * SEQ + k0 + cbs * 8, ld + q * 512);
        } else {
            bf16* l1 = &ldsB[wid - 2][0];   // wid2->nrTh, wid3->nrTl
            #pragma unroll
            for (int q = 0; q < 4; ++q)
                gload_lds16(sB1 + (size_t)(q * 8 + lrow) * SEQ + k0 + cbs * 8, l1 + q * 512);
            if (dual) {
                bf16* l2 = &ldsB[wid][0];   // wid2->niTh, wid3->niTl
                #pragma unroll
                for (int q = 0; q < 4; ++q)
                    gload_lds16(sB2 + (size_t)(q * 8 + lrow) * SEQ + k0 + cbs * 8, l2 + q * 512);
            }
        }
        __syncthreads();
        #pragma unroll
        for (int ks = 0; ks < 2; ++ks) {
            int cb = ks * 64 + (lane >> 4) * 16;
            int rowb = wc * 16 + (lane & 15);
            int offb = rowb * 128 + (cb ^ ((rowb & 7) << 4));
            bf16x8 brh = *(const bf16x8*)((const char*)&ldsB[0][0] + offb);
            bf16x8 brl = *(const bf16x8*)((const char*)&ldsB[1][0] + offb);
            #pragma unroll
            for (int fm = 0; fm < 2; ++fm) {
                int rowa = wr * 32 + fm * 16 + (lane & 15);
                int offa = rowa * 128 + (cb ^ ((rowa & 7) << 4));
                bf16x8 ah = *(const bf16x8*)((const char*)&ldsA[0][0] + offa);
                bf16x8 al = *(const bf16x8*)((const char*)&ldsA[1][0] + offa);
                accr[fm] = __builtin_amdgcn_mfma_f32_16x16x32_bf16(ah, brh, accr[fm], 0, 0, 0);
                accr[fm] = __builtin_amdgcn_mfma_f32_16x16x32_bf16(ah, brl, accr[fm], 0, 0, 0);
                accr[fm] = __builtin_amdgcn_mfma_f32_16x16x32_bf16(al, brh, accr[fm], 0, 0, 0);
            }
            if (dual) {
                bf16x8 bih = *(const bf16x8*)((const char*)&ldsB[2][0] + offb);
                bf16x8 bil = *(const bf16x8*)((const char*)&ldsB[3][0] + offb);
                #pragma unroll
                for (int fm = 0; fm < 2; ++fm) {
                    int rowa = wr * 32 + fm * 16 + (lane & 15);
                    int offa = rowa * 128 + (cb ^ ((rowa & 7) << 4));
                    bf16x8 ah = *(const bf16x8*)((const char*)&ldsA[0][0] + offa);
                    bf16x8 al = *(const bf16x8*)((const char*)&ldsA[1][0] + offa);
                    acci[fm] = __builtin_amdgcn_mfma_f32_16x16x32_bf16(ah, bih, acci[fm], 0, 0, 0);
                    acci[fm] = __builtin_amdgcn_mfma_f32_16x16x32_bf16(ah, bil, acci[fm], 0, 0, 0);
                    acci[fm] = __builtin_amdgcn_mfma_f32_16x16x32_bf16(al, bih, acci[fm], 0, 0, 0);
                }
            }
        }
        __syncthreads();
    }

    int d = d0 + wc * 16 + (lane & 15);
    #pragma unroll
    for (int fm = 0; fm < 2; ++fm) {
        int lb = l0 + wr * 32 + fm * 16 + (lane >> 4) * 4;
        #pragma unroll
        for (int i = 0; i < 4; ++i) {
            size_t idx = (size_t)(b * SEQ + lb + i) * DDIM + d;
            outr[idx] = accr[fm][i];
            if (dual) outi[idx] = acci[fm][i];
        }
    }
}

// coherence + phase preservation + residual LN update, fused with next-layer normphase
// (mode 0, sameRI) or with the final-LN prep (mode 1).
__global__ __launch_bounds__(256)
void update_kernel(float* __restrict__ realA,
                   const float* __restrict__ outr, const float* __restrict__ outi,
                   const float* __restrict__ C, const float* __restrict__ S,
                   const float* __restrict__ Cp, const float* __restrict__ Sp,
                   const void* __restrict__ pp, const void* __restrict__ cfac,
                   const void* __restrict__ energy, int layer, int mode,
                   const float* __restrict__ wmNext,
                   float* __restrict__ nrO, float* __restrict__ Co, float* __restrict__ So,
                   bf16* __restrict__ ASh, bf16* __restrict__ ASl,
                   bf16* __restrict__ BSh, bf16* __restrict__ BSl,
                   bf16* __restrict__ Ah, bf16* __restrict__ Al)
{
    __shared__ float red[4];
    bool bf = probe_bf(energy);
    int t = blockIdx.x, d = threadIdx.x;
    int b = t / SEQ;
    long idx = (long)t * DDIM + d;
    float cs = 0.f, ss = 0.f;
    #pragma unroll
    for (int c = 0; c < 24; ++c) {
        cs += Cp[(b * 24 + c) * DDIM + d];
        ss += Sp[(b * 24 + c) * DDIM + d];
    }
    float dotv = C[idx] * cs + S[idx] * ss;
    float coh = blk_sum256(dotv, red) * (1.0f / (384.f * 256.f));
    float cf = (1.f / (1.f + expf(-ldin(cfac, layer, bf)))) * coh;
    float orr = outr[idx], oii = outi[idx];
    float phase = atan2f(oii + 1e-8f, orr + 1e-8f);
    float pres = (1.f / (1.f + expf(-ldin(pp, layer * DDIM + d, bf)))) * cf;
    float pr = orr * cosf(phase * pres);
    float v = realA[idx] + 0.01f * pr;
    float mu = blk_sum256(v, red) * (1.f / 256.f);
    float dv = v - mu;
    float var = blk_sum256(dv * dv, red) * (1.f / 256.f);
    float nv = dv / sqrtf(var + 1e-8f);
    nv = fminf(fmaxf(nv, -1.f), 1.f);
    realA[idx] = nv;
    // fused LN(nv, 1e-5): feeds normphase (mode 0) or final comb (mode 1)
    float mu2 = blk_sum256(nv, red) * (1.f / 256.f);
    float dv2 = nv - mu2;
    float var2 = blk_sum256(dv2 * dv2, red) * (1.f / 256.f);
    float nn = dv2 / sqrtf(var2 + 1e-5f);
    if (mode == 0) {
        np_emit(t, d, nn, nn, false, wmNext, nrO, nullptr, Co, So, ASh, ASl, BSh, BSl);
    } else {
        bf16 h = __float2bfloat16(nn);
        Ah[idx] = h;
        Al[idx] = __float2bfloat16(nn - bf2f(h));
    }
}

// ---------------- Final stage: bf16x3 MFMA vocab GEMM ----------------

// Fold out_w halves (K=512 -> 256), transpose to [v][d] (K-major), split bf16 hi/lo.
__global__ __launch_bounds__(256)
void fold_kernel(const void* __restrict__ W, const void* __restrict__ energy,
                 bf16* __restrict__ Bh, bf16* __restrict__ Bl)
{
    __shared__ float tile[64][65];
    bool bf = probe_bf(energy);
    int v0 = blockIdx.x * 64, d0 = blockIdx.y * 64;
    int c = threadIdx.x & 63, rr = threadIdx.x >> 6;
    #pragma unroll
    for (int i = 0; i < 16; ++i) {
        int r = i * 4 + rr;
        long i1 = (long)(d0 + r) * VOC + v0 + c;
        long i2 = (long)(d0 + r + 256) * VOC + v0 + c;
        tile[r][c] = ldin(W, i1, bf) + ldin(W, i2, bf);
    }
    __syncthreads();
    int d = threadIdx.x & 63, vv = threadIdx.x >> 6;
    #pragma unroll
    for (int i = 0; i < 16; ++i) {
        int v = i * 4 + vv;
        float s = tile[d][v];
        bf16 h = __float2bfloat16(s);
        long o = (long)(v0 + v) * DDIM + d0 + d;
        Bh[o] = h;
        Bl[o] = __float2bfloat16(s - __bfloat162float(h));
    }
}

// C[m][n] = clip((sum_k comb[m][k]*Wf[n][k] + bias[n]) * 0.1).
// bf16x3: acc = ch*wh + ch*wl + cl*wh  (error ~2^-16 relative, f32-equivalent)
// Tiles: BM=128, BN=128, BK=64. 8 waves; wave (wm,wn) owns 64x32.
// XCD-aware bijective swizzle: 1500 blocks, q=187, r=4.
__global__ __launch_bounds__(512, 4)
void vocab_gemm(const bf16* __restrict__ Ah, const bf16* __restrict__ Al,
                const bf16* __restrict__ Bh, const bf16* __restrict__ Bl,
                const void* __restrict__ bias, const void* __restrict__ energy,
                void* __restrict__ out)
{
    __shared__ bf16 lds[4][128 * 64];   // Ah, Al, Bh, Bl tiles: [row][64k], 128 B rows
    bool bf = probe_bf(energy);
    int flat = blockIdx.x + blockIdx.y * 6;        // 0..1499
    int xcd = flat & 7, bidx = flat >> 3;
    int swz = (xcd < 4) ? xcd * 188 + bidx : 752 + (xcd - 4) * 187 + bidx;
    int m0 = (swz % 6) * 128, n0 = (swz / 6) * 128;
    int tid = threadIdx.x, lane = tid & 63, wid = tid >> 6;   // 8 waves
    int wm = wid >> 2, wn = wid & 3;
    int arr = wid >> 1, half = wid & 1;

    // wave pair (arr, half) stages rows [half*64, half*64+64) of tile arr
    const bf16* src;
    if      (arr == 0) src = Ah + (size_t)m0 * DDIM;
    else if (arr == 1) src = Al + (size_t)m0 * DDIM;
    else if (arr == 2) src = Bh + (size_t)n0 * DDIM;
    else               src = Bl + (size_t)n0 * DDIM;
    src += (size_t)half * 64 * DDIM;
    bf16* ldst = &lds[arr][half * 64 * 64];
    int lrow = lane >> 3;                    // row within 8-row group
    int cbs  = (lane & 7) ^ lrow;            // pre-swizzled source col-block (16 B units)

    f32x4 acc[4][2] = {};

    for (int k0 = 0; k0 < DDIM; k0 += 64) {
        #pragma unroll
        for (int q = 0; q < 8; ++q) {
            const bf16* g = src + (size_t)(q * 8 + lrow) * DDIM + k0 + cbs * 8;
            gload_lds16(g, ldst + q * 512);  // linear dest; source pre-swizzled
        }
        __syncthreads();                     // drains vmcnt before barrier

        #pragma unroll
        for (int ks = 0; ks < 2; ++ks) {
            int cb = ks * 64 + (lane >> 4) * 16;       // byte col for this lane's k-group
            bf16x8 bhf[2], blf[2];
            #pragma unroll
            for (int fn = 0; fn < 2; ++fn) {
                int row = wn * 32 + fn * 16 + (lane & 15);
                int off = row * 128 + (cb ^ ((row & 7) << 4));
                bhf[fn] = *(const bf16x8*)((const char*)&lds[2][0] + off);
                blf[fn] = *(const bf16x8*)((const char*)&lds[3][0] + off);
            }
            #pragma unroll
            for (int fm = 0; fm < 4; ++fm) {
                int row = wm * 64 + fm * 16 + (lane & 15);
                int off = row * 128 + (cb ^ ((row & 7) << 4));
                bf16x8 ah = *(const bf16x8*)((const char*)&lds[0][0] + off);
                bf16x8 al = *(const bf16x8*)((const char*)&lds[1][0] + off);
                #pragma unroll
                for (int fn = 0; fn < 2; ++fn) {
                    acc[fm][fn] = __builtin_amdgcn_mfma_f32_16x16x32_bf16(ah, bhf[fn], acc[fm][fn], 0, 0, 0);
                    acc[fm][fn] = __builtin_amdgcn_mfma_f32_16x16x32_bf16(ah, blf[fn], acc[fm][fn], 0, 0, 0);
                    acc[fm][fn] = __builtin_amdgcn_mfma_f32_16x16x32_bf16(al, bhf[fn], acc[fm][fn], 0, 0, 0);
                }
            }
        }
        __syncthreads();
    }

    // epilogue: D[row=(lane>>4)*4+i][col=lane&15] per 16x16 fragment
    #pragma unroll
    for (int fn = 0; fn < 2; ++fn) {
        int n = n0 + wn * 32 + fn * 16 + (lane & 15);
        float bv = ldin(bias, n, bf);
        #pragma unroll
        for (int fm = 0; fm < 4; ++fm) {
            int mbase = m0 + wm * 64 + fm * 16 + (lane >> 4) * 4;
            #pragma unroll
            for (int i = 0; i < 4; ++i) {
                float lg = (acc[fm][fn][i] + bv) * 0.1f;
                lg = fminf(fmaxf(lg, -10.f), 10.f);
                size_t idx = (size_t)(mbase + i) * VOC + n;
                if (bf) ((bf16*)out)[idx] = __float2bfloat16(lg);
                else    ((float*)out)[idx] = lg;
            }
        }
    }
}

extern "C" void kernel_launch(void* const* d_in, const int* in_sizes, int n_in,
                              void* d_out, int out_size, void* d_ws, size_t ws_size,
                              hipStream_t stream) {
    (void)in_sizes; (void)n_in; (void)out_size; (void)ws_size;
    const int*  x        = (const int*)d_in[0];
    const void* emb_real = d_in[1];
    // d_in[2] = emb_imag: unused downstream (matches reference)
    const void* lph      = d_in[3];
    const void* iw       = d_in[4];
    const void* energy   = d_in[5];
    const void* excf     = d_in[6];
    const void* pp       = d_in[7];
    const void* cfac     = d_in[8];
    const void* Wattn    = d_in[9];
    const void* out_w    = d_in[10];
    const void* out_b    = d_in[11];

    float* ws = (float*)d_ws;
    const int TD = NTOK * DDIM;   // 196608
    float* realA = ws;            // residual state
    float* nr    = realA + TD;
    float* ni    = nr + TD;       // only used layer 0
    float* Cc    = ni + TD;
    float* Ss    = Cc + TD;
    float* outr  = Ss + TD;
    float* outi  = outr + TD;     // only written layer 0
    float* attn  = outi + TD;     // 2*384*384 f32 scores
    float* Cp    = attn + 2 * SEQ * SEQ;   // 48*256
    float* Sp    = Cp + 48 * DDIM;
    float* wmAll = Sp + 48 * DDIM;         // 768 floats
    // bf16 buffers (all offsets multiples of 8 elems -> 16B aligned)
    bf16* Ah  = (bf16*)(wmAll + 768);
    bf16* Al  = Ah + (size_t)NTOK * DDIM;
    bf16* Wth = Al + (size_t)NTOK * DDIM;
    bf16* Wtl = Wth + (size_t)VOC * DDIM;
    bf16* ASh = Wtl + (size_t)VOC * DDIM;
    bf16* ASl = ASh + (size_t)NTOK * 512;
    bf16* BSh = ASl + (size_t)NTOK * 512;
    bf16* BSl = BSh + (size_t)NTOK * 512;
    bf16* Phb = BSl + (size_t)NTOK * 512;      // P hi: [768][384]
    bf16* Plb = Phb + (size_t)NTOK * SEQ;
    bf16* nrTh = Plb + (size_t)NTOK * SEQ;     // [2][256][384]
    bf16* nrTl = nrTh + (size_t)NTOK * DDIM;
    bf16* niTh = nrTl + (size_t)NTOK * DDIM;
    bf16* niTl = niTh + (size_t)NTOK * DDIM;

    // independent precomputes
    fold_kernel<<<dim3(VOC / 64, DDIM / 64), 256, 0, stream>>>(out_w, energy, Wth, Wtl);
    wmean_kernel<<<192, 256, 0, stream>>>(Wattn, energy, wmAll);

    // embedding + phase space + normphase(layer 0)
    phase_kernel<<<NTOK, 256, 0, stream>>>(x, emb_real, lph, iw, energy, excf, wmAll,
                                           realA, nr, ni, Cc, Ss, ASh, ASl, BSh, BSl);
    for (int layer = 0; layer < 3; ++layer) {
        int dual = (layer == 0);
        sums_kernel<<<dim3(24, 2), 256, 0, stream>>>(Cc, Ss, Cp, Sp);
        transpose_kernel<<<dim3(6, 4, 2), 256, 0, stream>>>(nr, ni, nrTh, nrTl, niTh, niTl, dual);
        scores_mfma<<<dim3(6, 12, 2), 256, 0, stream>>>(ASh, ASl, BSh, BSl, attn);
        softmax_kernel<<<NTOK, 384, 0, stream>>>(attn, x, Phb, Plb);
        outgemm_mfma<<<dim3(6, 8, 2), 256, 0, stream>>>(Phb, Plb, nrTh, nrTl, niTh, niTl,
                                                        outr, outi, dual);
        // layers 1,2: out_i == out_r bit-exactly (imag == real), pass outr twice
        update_kernel<<<NTOK, 256, 0, stream>>>(realA, outr, dual ? outi : outr, Cc, Ss,
                                                Cp, Sp, pp, cfac, energy, layer,
                                                (layer < 2) ? 0 : 1,
                                                wmAll + (layer + 1 < 3 ? (layer + 1) * DDIM : 0),
                                                nr, Cc, Ss, ASh, ASl, BSh, BSl, Ah, Al);
    }
    vocab_gemm<<<dim3(6, VOC / 128), 512, 0, stream>>>(Ah, Al, Wth, Wtl, out_b, energy, (void*)d_out);
}